// Round 25
// baseline (90.283 us; speedup 1.0000x reference)
//
#include <hip/hip_runtime.h>
#include <hip/hip_bf16.h>

#define BATCH 4
#define NSEQ  4096
#define CDIM  256
#define CQK   32
#define L2E   1.44269504088896340736f

typedef short bf16x8 __attribute__((ext_vector_type(8)));   // 8 bf16 in 4 VGPRs
typedef float f32x16 __attribute__((ext_vector_type(16)));
typedef unsigned short u16;
typedef unsigned int   u32;
typedef unsigned int   u32x4 __attribute__((ext_vector_type(4)));

__device__ __forceinline__ u32 pk2(float lo, float hi) {    // v_cvt_pk_bf16_f32
  u16 a = __builtin_bit_cast(u16, __float2bfloat16(lo));
  u16 b = __builtin_bit_cast(u16, __float2bfloat16(hi));
  return (u32)a | ((u32)b << 16);
}
__device__ __forceinline__ bf16x8 ld8(const u16* p) {
  uint4 u = *(const uint4*)p;
  return __builtin_bit_cast(bf16x8, u);
}
// raw v_exp_f32 via builtin (hazard-safe; inline-asm version failed r9 at absmax 2.69)
__device__ __forceinline__ float exp2_raw(float x) {
#if __has_builtin(__builtin_amdgcn_exp2f)
  return __builtin_amdgcn_exp2f(x);
#else
  return exp2f(x);
#endif
}

// ---------------- weight prep: W[k][c] (f32) -> WT[c][k] (bf16); WfT pre-scaled by L2E --
__global__ __launch_bounds__(64) void prep_kernel(
    const float* __restrict__ Wf, const float* __restrict__ Wg, const float* __restrict__ Wh,
    u16* __restrict__ wfT, u16* __restrict__ wgT, u16* __restrict__ whT) {
  const int cb = blockIdx.x, t = threadIdx.x;
#pragma unroll
  for (int j = 0; j < 4; ++j) {
    const int k = t + j * 64;
    if (cb < 32) {
      wfT[cb * 256 + k] = (u16)(pk2(Wf[k * CQK + cb] * L2E, 0.f) & 0xFFFF);
    } else if (cb < 64) {
      const int c = cb - 32;
      wgT[c * 256 + k] = (u16)(pk2(Wg[k * CQK + c], 0.f) & 0xFFFF);
    } else {
      const int c = cb - 64;
      whT[c * 256 + k] = (u16)(pk2(Wh[k * CDIM + c], 0.f) & 0xFFFF);
    }
  }
}

// ---------------- MFMA projection -> FRAGMENT-PACKED outputs (r23 measured-good) --------
// grid 512 (32 rows/block), 4 waves split work: w0: f+h{0,1}, w1: g+h{2,3},
// w2: h{4,5}, w3: h{6,7}. launch_bounds(256,2) -> 2 waves/SIMD.
// fP[b*128+kc][ks(2)][lane(64)][8]  : A-frag tiles for QK   (kc = 32-key chunk)
// hP[(b*8+cg)*128+kc][ks(2)][lane(64)][8] : B-frag tiles for PV (cg = 32-ch group)
__global__ __launch_bounds__(256, 2) void proj_kernel(
    const float* __restrict__ x,
    const float* __restrict__ bfv, const float* __restrict__ bgv, const float* __restrict__ bhv,
    const u16* __restrict__ wfT, const u16* __restrict__ wgT, const u16* __restrict__ whT,
    u16* __restrict__ fP, u16* __restrict__ g_ws, u16* __restrict__ hP) {
  const int tid   = threadIdx.x;
  const int lan   = tid & 63;
  const int lan31 = lan & 31;
  const int g2    = lan >> 5;
  const int w     = tid >> 6;                   // wave 0..3
  const int row0  = blockIdx.x * 32;            // 32 rows = one key chunk
  const int b     = row0 >> 12;
  const int kcg   = row0 >> 5;                  // global kc = b*128 + (row0&4095)>>5

  // x fragments (each wave loads the block's 32 rows; redundant but L1/L2-cached)
  bf16x8 xf[16];
  const float* xr = x + ((size_t)row0 + lan31) * CDIM + g2 * 8;
#pragma unroll
  for (int ks = 0; ks < 16; ++ks) {
    float4 a = *(const float4*)(xr + ks * 16);
    float4 c = *(const float4*)(xr + ks * 16 + 4);
    u32x4 u = { pk2(a.x, a.y), pk2(a.z, a.w), pk2(c.x, c.y), pk2(c.z, c.w) };
    xf[ks] = __builtin_bit_cast(bf16x8, u);
  }

  if (w < 2) { // w0: f (packed), w1: g (row-major): D[m=row(key)][n=c]
    const u16*  wT   = w ? wgT : wfT;
    const float bias = w ? bgv[lan31] : bfv[lan31] * L2E;
    f32x16 acc;
#pragma unroll
    for (int r = 0; r < 16; ++r) acc[r] = bias;
    const u16* wp = wT + lan31 * 256 + g2 * 8;
#pragma unroll
    for (int ks = 0; ks < 16; ++ks)
      acc = __builtin_amdgcn_mfma_f32_32x32x16_bf16(xf[ks], ld8(wp + ks * 16), acc, 0, 0, 0);
    if (w) {
#pragma unroll
      for (int r = 0; r < 16; ++r) {
        const int row = (r & 3) + 8 * (r >> 2) + 4 * g2;
        g_ws[((size_t)row0 + row) * CQK + lan31] = (u16)(pk2(acc[r], 0.f) & 0xFFFF);
      }
    } else {
      u16* fb = fP + (size_t)kcg * 1024
              + (lan31 >> 4) * 512 + ((lan31 >> 3) & 1) * 256 + (lan31 & 7);
#pragma unroll
      for (int r = 0; r < 16; ++r) {
        const int crow = (r & 3) + 8 * (r >> 2) + 4 * g2;   // key row within chunk
        fb[crow * 8] = (u16)(pk2(acc[r], 0.f) & 0xFFFF);
      }
    }
  }

  // h: wave w handles channel groups {2w, 2w+1}; D[m=c][n=row(key)] via swapped operands
#pragma unroll
  for (int t = 0; t < 2; ++t) {
    const int cg = w * 2 + t;
    const int ct = cg * 32;
    f32x16 acc;
#pragma unroll
    for (int r = 0; r < 16; ++r)
      acc[r] = bhv[ct + (r & 3) + 8 * (r >> 2) + 4 * g2];
    const u16* wp = whT + (size_t)(ct + lan31) * 256 + g2 * 8;
#pragma unroll
    for (int ks = 0; ks < 16; ++ks)
      acc = __builtin_amdgcn_mfma_f32_32x32x16_bf16(ld8(wp + ks * 16), xf[ks], acc, 0, 0, 0);
    u16* hb = hP + ((size_t)(b * 8 + cg) * 128 + ((row0 & (NSEQ - 1)) >> 5)) * 1024
            + (lan31 >> 4) * 512 + ((lan31 >> 3) & 1) * 256 + (lan31 & 7);
#pragma unroll
    for (int r = 0; r < 16; ++r) {
      const int crow = (r & 3) + 8 * (r >> 2) + 4 * g2;     // channel row within group
      hb[crow * 8] = (u16)(pk2(acc[r], 0.f) & 0xFFFF);
    }
  }
}

// ---------------- flash attention: barrier-free + softmax pipelined 1 chunk ahead -------
// Grid 512 = 4b x 64 q-tiles(64q) x 2 cb -> 2 independent blocks/CU. Block = 4 waves =
// 4 key-splits; wave (kw): 64q x 128ch x 1024 keys. T15 pipeline: iteration it computes
// softmax(it+1) (VALU/TRANS) BEFORE PV(it) (MFMA) — no mutual dependency, pipes overlap.
// Register-neutral: +16 apc/apn, -16 rolling 2-deep h buffer, -8 no naf pair.
// Tail: softmax(32) computed but discarded (reads land in g_ws, in-bounds); l2 guarded.
// NO setprio (r23 A/B: regresses cross-block overlap).
__global__ __launch_bounds__(256, 2) void attn_kernel(
    const float* __restrict__ x, const float* __restrict__ gamma_p,
    const u16* __restrict__ fP, const u16* __restrict__ g_ws,
    const u16* __restrict__ hP, float* __restrict__ out) {
  __shared__ u32   pls[4][2][2][16][64];        // [kw][cgp][qh][r][lane] 64KB combine
  __shared__ float lsh[4][2][64];               // [kw][qh][lane] 2KB

  const int tid   = threadIdx.x;
  const int lan   = tid & 63;
  const int lan31 = lan & 31;
  const int g2    = lan >> 5;
  const int kw    = tid >> 6;                   // wave id = key split 0..3
  const int bid   = blockIdx.x;
  const int xcd   = bid & 7;
  const int b     = xcd >> 1;
  const int inner = bid >> 3;                   // 0..63
  const int cb    = inner & 1;                  // channel block 0/1 (128 ch)
  const int n0    = ((((xcd & 1) << 5) | (inner >> 1))) * 64;

  const float gamma = gamma_p[0];

  // g fragments for both 32-query tiles
  bf16x8 bgM[2][2];
#pragma unroll
  for (int qh = 0; qh < 2; ++qh) {
    const u16* gp = g_ws + ((size_t)b * NSEQ + n0 + qh * 32 + lan31) * CQK + g2 * 8;
    bgM[qh][0] = ld8(gp);
    bgM[qh][1] = ld8(gp + 16);
  }

  f32x16 o[4][2], zfrag;                        // [cg][qh] = 128 acc regs
#pragma unroll
  for (int r = 0; r < 16; ++r) zfrag[r] = 0.f;
#pragma unroll
  for (int cg = 0; cg < 4; ++cg) { o[cg][0] = zfrag; o[cg][1] = zfrag; }
  float l2[2] = {0.f, 0.f};

  const u16*  fpk = fP + (size_t)(b * 128 + kw * 32) * 1024 + lan * 8;
  const u16*  hpk = hP + ((size_t)(b * 8 + cb * 4) * 128 + kw * 32) * 1024 + lan * 8;
  const size_t hcg = (size_t)128 * 1024;        // cg stride in elems

  bf16x8 af0, af1;                              // f frags of the NEXT softmax chunk
  bf16x8 apc[2][2], apn[2][2];                  // P A-frags: current / next

  // softmax of the chunk held in af -> dst; l2 accumulated only when do_l
  auto sm_step = [&](bool do_l, bf16x8 (&dst)[2][2]) {
#pragma unroll
    for (int qh = 0; qh < 2; ++qh) {
      f32x16 s = __builtin_amdgcn_mfma_f32_32x32x16_bf16(af0, bgM[qh][0], zfrag, 0, 0, 0);
      s        = __builtin_amdgcn_mfma_f32_32x32x16_bf16(af1, bgM[qh][1], s,     0, 0, 0);
      float pv[16];
#pragma unroll
      for (int r = 0; r < 16; ++r) pv[r] = exp2_raw(s[r]);
      if (do_l) {
        float rs = ((pv[0]+pv[1])+(pv[2]+pv[3])) + ((pv[4]+pv[5])+(pv[6]+pv[7]))
                 + ((pv[8]+pv[9])+(pv[10]+pv[11])) + ((pv[12]+pv[13])+(pv[14]+pv[15]));
        auto rr = __builtin_amdgcn_permlane32_swap(__builtin_bit_cast(u32, rs),
                                                   __builtin_bit_cast(u32, rs), false, false);
        l2[qh] += __builtin_bit_cast(float, (u32)rr[0]) + __builtin_bit_cast(float, (u32)rr[1]);
      }
      u32 q0a = pk2(pv[0],pv[1]),   q0b = pk2(pv[2],pv[3]);
      u32 q1a = pk2(pv[4],pv[5]),   q1b = pk2(pv[6],pv[7]);
      u32 q2a = pk2(pv[8],pv[9]),   q2b = pk2(pv[10],pv[11]);
      u32 q3a = pk2(pv[12],pv[13]), q3b = pk2(pv[14],pv[15]);
      auto r02a = __builtin_amdgcn_permlane32_swap(q0a, q1a, false, false);
      auto r13a = __builtin_amdgcn_permlane32_swap(q0b, q1b, false, false);
      auto r02b = __builtin_amdgcn_permlane32_swap(q2a, q3a, false, false);
      auto r13b = __builtin_amdgcn_permlane32_swap(q2b, q3b, false, false);
      u32x4 u0 = {(u32)r02a[0], (u32)r13a[0], (u32)r02a[1], (u32)r13a[1]};
      u32x4 u1 = {(u32)r02b[0], (u32)r13b[0], (u32)r02b[1], (u32)r13b[1]};
      dst[qh][0] = __builtin_bit_cast(bf16x8, u0);
      dst[qh][1] = __builtin_bit_cast(bf16x8, u1);
    }
  };

  // prologue: softmax(chunk 0) -> apc (with l); then af <- chunk 1
  af0 = ld8(fpk); af1 = ld8(fpk + 512); fpk += 1024;
  sm_step(true, apc);
  af0 = ld8(fpk); af1 = ld8(fpk + 512); fpk += 1024;

  for (int it = 0; it < 32; ++it) {
    // issue h(it) cg0 pair (lands during softmax below)
    bf16x8 hA0 = ld8(hpk),       hA1 = ld8(hpk + 512);

    // softmax(it+1): chunks 1..31 accumulate l; it=31 computes a discarded tail
    sm_step(it < 31, apn);

    // reload af with chunk it+2 (consumed next iteration; covered by PV block)
    af0 = ld8(fpk); af1 = ld8(fpk + 512); fpk += 1024;

    // issue h cg1 pair before PV cg0
    bf16x8 hB0 = ld8(hpk + hcg), hB1 = ld8(hpk + hcg + 512);

    // PV cg0 (hA), then roll hA -> cg2
    o[0][0] = __builtin_amdgcn_mfma_f32_32x32x16_bf16(apc[0][0], hA0, o[0][0], 0, 0, 0);
    o[0][0] = __builtin_amdgcn_mfma_f32_32x32x16_bf16(apc[0][1], hA1, o[0][0], 0, 0, 0);
    o[0][1] = __builtin_amdgcn_mfma_f32_32x32x16_bf16(apc[1][0], hA0, o[0][1], 0, 0, 0);
    o[0][1] = __builtin_amdgcn_mfma_f32_32x32x16_bf16(apc[1][1], hA1, o[0][1], 0, 0, 0);
    hA0 = ld8(hpk + 2 * hcg); hA1 = ld8(hpk + 2 * hcg + 512);

    // PV cg1 (hB), then roll hB -> cg3
    o[1][0] = __builtin_amdgcn_mfma_f32_32x32x16_bf16(apc[0][0], hB0, o[1][0], 0, 0, 0);
    o[1][0] = __builtin_amdgcn_mfma_f32_32x32x16_bf16(apc[0][1], hB1, o[1][0], 0, 0, 0);
    o[1][1] = __builtin_amdgcn_mfma_f32_32x32x16_bf16(apc[1][0], hB0, o[1][1], 0, 0, 0);
    o[1][1] = __builtin_amdgcn_mfma_f32_32x32x16_bf16(apc[1][1], hB1, o[1][1], 0, 0, 0);
    hB0 = ld8(hpk + 3 * hcg); hB1 = ld8(hpk + 3 * hcg + 512);

    // PV cg2 (hA), PV cg3 (hB)
    o[2][0] = __builtin_amdgcn_mfma_f32_32x32x16_bf16(apc[0][0], hA0, o[2][0], 0, 0, 0);
    o[2][0] = __builtin_amdgcn_mfma_f32_32x32x16_bf16(apc[0][1], hA1, o[2][0], 0, 0, 0);
    o[2][1] = __builtin_amdgcn_mfma_f32_32x32x16_bf16(apc[1][0], hA0, o[2][1], 0, 0, 0);
    o[2][1] = __builtin_amdgcn_mfma_f32_32x32x16_bf16(apc[1][1], hA1, o[2][1], 0, 0, 0);
    o[3][0] = __builtin_amdgcn_mfma_f32_32x32x16_bf16(apc[0][0], hB0, o[3][0], 0, 0, 0);
    o[3][0] = __builtin_amdgcn_mfma_f32_32x32x16_bf16(apc[0][1], hB1, o[3][0], 0, 0, 0);
    o[3][1] = __builtin_amdgcn_mfma_f32_32x32x16_bf16(apc[1][0], hB0, o[3][1], 0, 0, 0);
    o[3][1] = __builtin_amdgcn_mfma_f32_32x32x16_bf16(apc[1][1], hB1, o[3][1], 0, 0, 0);

    hpk += 1024;
    apc[0][0] = apn[0][0]; apc[0][1] = apn[0][1];
    apc[1][0] = apn[1][0]; apc[1][1] = apn[1][1];
  }

  // ---- one-time kw-combine: bf16-packed partials through LDS ----
  lsh[kw][0][lan] = l2[0];
  lsh[kw][1][lan] = l2[1];
#pragma unroll
  for (int cgp = 0; cgp < 2; ++cgp)
#pragma unroll
    for (int qh = 0; qh < 2; ++qh)
#pragma unroll
      for (int r = 0; r < 16; ++r)
        pls[kw][cgp][qh][r][lan] = pk2(o[cgp * 2][qh][r], o[cgp * 2 + 1][qh][r]);
  __syncthreads();

  const int cgp = kw >> 1, qh = kw & 1;         // this wave's output slice
  float e0[16], e1[16];
#pragma unroll
  for (int r = 0; r < 16; ++r) { e0[r] = 0.f; e1[r] = 0.f; }
#pragma unroll
  for (int kk = 0; kk < 4; ++kk)
#pragma unroll
    for (int r = 0; r < 16; ++r) {
      u32 v = pls[kk][cgp][qh][r][lan];
      e0[r] += __builtin_bit_cast(float, v << 16);
      e1[r] += __builtin_bit_cast(float, v & 0xFFFF0000u);
    }
  const float l_tot = lsh[0][qh][lan] + lsh[1][qh][lan]
                    + lsh[2][qh][lan] + lsh[3][qh][lan];
  const float gi = gamma / l_tot;
#pragma unroll
  for (int r = 0; r < 16; ++r) {
    const int nl = (r & 3) + 8 * (r >> 2) + 4 * g2;
    const float gir = __shfl(gi, nl);
    const size_t row = (size_t)b * NSEQ + n0 + qh * 32 + nl;
    const size_t i0 = row * CDIM + cb * 128 + cgp * 64 + lan31;
    out[i0]      = fmaf(gir, e0[r], x[i0]);
    out[i0 + 32] = fmaf(gir, e1[r], x[i0 + 32]);
  }
}

extern "C" void kernel_launch(void* const* d_in, const int* in_sizes, int n_in,
                              void* d_out, int out_size, void* d_ws, size_t ws_size,
                              hipStream_t stream) {
  const float* x     = (const float*)d_in[0];
  const float* Wf    = (const float*)d_in[1];
  const float* bf    = (const float*)d_in[2];
  const float* Wg    = (const float*)d_in[3];
  const float* bg    = (const float*)d_in[4];
  const float* Wh    = (const float*)d_in[5];
  const float* bh    = (const float*)d_in[6];
  const float* gamma = (const float*)d_in[7];
  float* out = (float*)d_out;

  // layout: hP | fP | g | wfT | wgT | whT  (fP before g so f-prefetch overrun lands in g)
  u16* hP   = (u16*)d_ws;                                    // 8 MB
  u16* fPp  = hP  + (size_t)BATCH * CDIM * NSEQ;             // 1 MB
  u16* g_ws = fPp + (size_t)BATCH * NSEQ * CQK;              // 1 MB
  u16* wfT  = g_ws + (size_t)BATCH * NSEQ * CQK;             // 16 KB
  u16* wgT  = wfT + (size_t)CQK * CDIM;                      // 16 KB
  u16* whT  = wgT + (size_t)CQK * CDIM;                      // 128 KB

  hipLaunchKernelGGL(prep_kernel, dim3(320), dim3(64), 0, stream,
                     Wf, Wg, Wh, wfT, wgT, whT);
  hipLaunchKernelGGL(proj_kernel, dim3(512), dim3(256), 0, stream,
                     x, bf, bg, bh, wfT, wgT, whT, fPp, g_ws, hP);
  hipLaunchKernelGGL(attn_kernel, dim3(512), dim3(256), 0, stream,
                     x, gamma, fPp, g_ws, hP, out);
}

// Round 26
// 80.433 us; speedup vs baseline: 1.1225x; 1.1225x over previous
//
#include <hip/hip_runtime.h>
#include <hip/hip_bf16.h>

#define BATCH 4
#define NSEQ  4096
#define CDIM  256
#define CQK   32
#define L2E   1.44269504088896340736f

typedef short bf16x8 __attribute__((ext_vector_type(8)));   // 8 bf16 in 4 VGPRs
typedef float f32x16 __attribute__((ext_vector_type(16)));
typedef unsigned short u16;
typedef unsigned int   u32;
typedef unsigned int   u32x4 __attribute__((ext_vector_type(4)));

__device__ __forceinline__ u32 pk2(float lo, float hi) {    // v_cvt_pk_bf16_f32
  u16 a = __builtin_bit_cast(u16, __float2bfloat16(lo));
  u16 b = __builtin_bit_cast(u16, __float2bfloat16(hi));
  return (u32)a | ((u32)b << 16);
}
__device__ __forceinline__ bf16x8 ld8(const u16* p) {
  uint4 u = *(const uint4*)p;
  return __builtin_bit_cast(bf16x8, u);
}
// raw v_exp_f32 via builtin (hazard-safe; inline-asm version failed r9 at absmax 2.69)
__device__ __forceinline__ float exp2_raw(float x) {
#if __has_builtin(__builtin_amdgcn_exp2f)
  return __builtin_amdgcn_exp2f(x);
#else
  return exp2f(x);
#endif
}

// ---------------- weight prep: W[k][c] (f32) -> WT[c][k] (bf16); WfT pre-scaled by L2E --
__global__ __launch_bounds__(64) void prep_kernel(
    const float* __restrict__ Wf, const float* __restrict__ Wg, const float* __restrict__ Wh,
    u16* __restrict__ wfT, u16* __restrict__ wgT, u16* __restrict__ whT) {
  const int cb = blockIdx.x, t = threadIdx.x;
#pragma unroll
  for (int j = 0; j < 4; ++j) {
    const int k = t + j * 64;
    if (cb < 32) {
      wfT[cb * 256 + k] = (u16)(pk2(Wf[k * CQK + cb] * L2E, 0.f) & 0xFFFF);
    } else if (cb < 64) {
      const int c = cb - 32;
      wgT[c * 256 + k] = (u16)(pk2(Wg[k * CQK + c], 0.f) & 0xFFFF);
    } else {
      const int c = cb - 64;
      whT[c * 256 + k] = (u16)(pk2(Wh[k * CDIM + c], 0.f) & 0xFFFF);
    }
  }
}

// ---------------- MFMA projection -> FRAGMENT-PACKED outputs ----------------------------
// grid 512 (32 rows/block), 4 waves split work: w0: f+h{0,1}, w1: g+h{2,3},
// w2: h{4,5}, w3: h{6,7}. launch_bounds(256,2) -> 2 waves/SIMD (r23: measured win).
// fP[b*128+kc][ks(2)][lane(64)][8]  : A-frag tiles for QK   (kc = 32-key chunk)
// hP[(b*8+cg)*128+kc][ks(2)][lane(64)][8] : B-frag tiles for PV (cg = 32-ch group)
__global__ __launch_bounds__(256, 2) void proj_kernel(
    const float* __restrict__ x,
    const float* __restrict__ bfv, const float* __restrict__ bgv, const float* __restrict__ bhv,
    const u16* __restrict__ wfT, const u16* __restrict__ wgT, const u16* __restrict__ whT,
    u16* __restrict__ fP, u16* __restrict__ g_ws, u16* __restrict__ hP) {
  const int tid   = threadIdx.x;
  const int lan   = tid & 63;
  const int lan31 = lan & 31;
  const int g2    = lan >> 5;
  const int w     = tid >> 6;                   // wave 0..3
  const int row0  = blockIdx.x * 32;            // 32 rows = one key chunk
  const int b     = row0 >> 12;
  const int kcg   = row0 >> 5;                  // global kc = b*128 + (row0&4095)>>5

  // x fragments (each wave loads the block's 32 rows; redundant but L1/L2-cached)
  bf16x8 xf[16];
  const float* xr = x + ((size_t)row0 + lan31) * CDIM + g2 * 8;
#pragma unroll
  for (int ks = 0; ks < 16; ++ks) {
    float4 a = *(const float4*)(xr + ks * 16);
    float4 c = *(const float4*)(xr + ks * 16 + 4);
    u32x4 u = { pk2(a.x, a.y), pk2(a.z, a.w), pk2(c.x, c.y), pk2(c.z, c.w) };
    xf[ks] = __builtin_bit_cast(bf16x8, u);
  }

  if (w < 2) { // w0: f (packed), w1: g (row-major): D[m=row(key)][n=c]
    const u16*  wT   = w ? wgT : wfT;
    const float bias = w ? bgv[lan31] : bfv[lan31] * L2E;
    f32x16 acc;
#pragma unroll
    for (int r = 0; r < 16; ++r) acc[r] = bias;
    const u16* wp = wT + lan31 * 256 + g2 * 8;
#pragma unroll
    for (int ks = 0; ks < 16; ++ks)
      acc = __builtin_amdgcn_mfma_f32_32x32x16_bf16(xf[ks], ld8(wp + ks * 16), acc, 0, 0, 0);
    if (w) {
#pragma unroll
      for (int r = 0; r < 16; ++r) {
        const int row = (r & 3) + 8 * (r >> 2) + 4 * g2;
        g_ws[((size_t)row0 + row) * CQK + lan31] = (u16)(pk2(acc[r], 0.f) & 0xFFFF);
      }
    } else {
      u16* fb = fP + (size_t)kcg * 1024
              + (lan31 >> 4) * 512 + ((lan31 >> 3) & 1) * 256 + (lan31 & 7);
#pragma unroll
      for (int r = 0; r < 16; ++r) {
        const int crow = (r & 3) + 8 * (r >> 2) + 4 * g2;   // key row within chunk
        fb[crow * 8] = (u16)(pk2(acc[r], 0.f) & 0xFFFF);
      }
    }
  }

  // h: wave w handles channel groups {2w, 2w+1}; D[m=c][n=row(key)] via swapped operands
#pragma unroll
  for (int t = 0; t < 2; ++t) {
    const int cg = w * 2 + t;
    const int ct = cg * 32;
    f32x16 acc;
#pragma unroll
    for (int r = 0; r < 16; ++r)
      acc[r] = bhv[ct + (r & 3) + 8 * (r >> 2) + 4 * g2];
    const u16* wp = whT + (size_t)(ct + lan31) * 256 + g2 * 8;
#pragma unroll
    for (int ks = 0; ks < 16; ++ks)
      acc = __builtin_amdgcn_mfma_f32_32x32x16_bf16(ld8(wp + ks * 16), xf[ks], acc, 0, 0, 0);
    u16* hb = hP + ((size_t)(b * 8 + cg) * 128 + ((row0 & (NSEQ - 1)) >> 5)) * 1024
            + (lan31 >> 4) * 512 + ((lan31 >> 3) & 1) * 256 + (lan31 & 7);
#pragma unroll
    for (int r = 0; r < 16; ++r) {
      const int crow = (r & 3) + 8 * (r >> 2) + 4 * g2;     // channel row within group
      hb[crow * 8] = (u16)(pk2(acc[r], 0.f) & 0xFFFF);
    }
  }
}

// ---------------- flash attention: barrier-free main loop (r22/r24 proven 54.6us) -------
// Grid 512 = 4b x 64 q-tiles(64q) x 2 cb -> 2 independent blocks/CU. Block = 4 waves =
// 4 key-splits; wave (kw): 64q x 128ch x 1024 keys. P consumed in-register; zero in-loop
// barriers/LDS; one-time kw-combine epilogue.
// Measured dead ends from this config: setprio (r23 +10%), owner-rotation (r19 +60%),
// forced 4 waves/SIMD (r20 spill +690%), softmax pipelining (r25 +24%). Cross-block
// wave overlap at 2 blocks/CU IS the latency hiding; register budget (128 acc + ~116
// VGPR ~= 244/256) pins occupancy and unroll depth.
__global__ __launch_bounds__(256, 2) void attn_kernel(
    const float* __restrict__ x, const float* __restrict__ gamma_p,
    const u16* __restrict__ fP, const u16* __restrict__ g_ws,
    const u16* __restrict__ hP, float* __restrict__ out) {
  __shared__ u32   pls[4][2][2][16][64];        // [kw][cgp][qh][r][lane] 64KB combine
  __shared__ float lsh[4][2][64];               // [kw][qh][lane] 2KB

  const int tid   = threadIdx.x;
  const int lan   = tid & 63;
  const int lan31 = lan & 31;
  const int g2    = lan >> 5;
  const int kw    = tid >> 6;                   // wave id = key split 0..3
  const int bid   = blockIdx.x;
  const int xcd   = bid & 7;
  const int b     = xcd >> 1;
  const int inner = bid >> 3;                   // 0..63
  const int cb    = inner & 1;                  // channel block 0/1 (128 ch)
  const int n0    = ((((xcd & 1) << 5) | (inner >> 1))) * 64;

  const float gamma = gamma_p[0];

  // g fragments for both 32-query tiles
  bf16x8 bgM[2][2];
#pragma unroll
  for (int qh = 0; qh < 2; ++qh) {
    const u16* gp = g_ws + ((size_t)b * NSEQ + n0 + qh * 32 + lan31) * CQK + g2 * 8;
    bgM[qh][0] = ld8(gp);
    bgM[qh][1] = ld8(gp + 16);
  }

  f32x16 o[4][2], zfrag;                        // [cg][qh] = 128 acc regs
#pragma unroll
  for (int r = 0; r < 16; ++r) zfrag[r] = 0.f;
#pragma unroll
  for (int cg = 0; cg < 4; ++cg) { o[cg][0] = zfrag; o[cg][1] = zfrag; }
  float l2[2] = {0.f, 0.f};

  const u16*  fpk = fP + (size_t)(b * 128 + kw * 32) * 1024 + lan * 8;
  const u16*  hpk = hP + ((size_t)(b * 8 + cb * 4) * 128 + kw * 32) * 1024 + lan * 8;
  const size_t hcg = (size_t)128 * 1024;        // cg stride in elems

  bf16x8 af0 = ld8(fpk), af1 = ld8(fpk + 512);
  fpk += 1024;

  for (int it = 0; it < 32; ++it) {
    bf16x8 naf0 = ld8(fpk), naf1 = ld8(fpk + 512);          // f prefetch (overrun -> g_ws)
    fpk += 1024;
    bf16x8 ha[4], hb[4];                        // h loads hide under softmax
#pragma unroll
    for (int cg = 0; cg < 4; ++cg) {
      ha[cg] = ld8(hpk + cg * hcg);
      hb[cg] = ld8(hpk + cg * hcg + 512);
    }
    hpk += 1024;

#pragma unroll
    for (int qh = 0; qh < 2; ++qh) {
      f32x16 s = __builtin_amdgcn_mfma_f32_32x32x16_bf16(af0, bgM[qh][0], zfrag, 0, 0, 0);
      s        = __builtin_amdgcn_mfma_f32_32x32x16_bf16(af1, bgM[qh][1], s,     0, 0, 0);

      float pv[16];
#pragma unroll
      for (int r = 0; r < 16; ++r) pv[r] = exp2_raw(s[r]);
      float rs = ((pv[0]+pv[1])+(pv[2]+pv[3])) + ((pv[4]+pv[5])+(pv[6]+pv[7]))
               + ((pv[8]+pv[9])+(pv[10]+pv[11])) + ((pv[12]+pv[13])+(pv[14]+pv[15]));
      auto rr = __builtin_amdgcn_permlane32_swap(__builtin_bit_cast(u32, rs),
                                                 __builtin_bit_cast(u32, rs), false, false);
      l2[qh] += __builtin_bit_cast(float, (u32)rr[0]) + __builtin_bit_cast(float, (u32)rr[1]);

      u32 q0a = pk2(pv[0],pv[1]),   q0b = pk2(pv[2],pv[3]);
      u32 q1a = pk2(pv[4],pv[5]),   q1b = pk2(pv[6],pv[7]);
      u32 q2a = pk2(pv[8],pv[9]),   q2b = pk2(pv[10],pv[11]);
      u32 q3a = pk2(pv[12],pv[13]), q3b = pk2(pv[14],pv[15]);
      auto r02a = __builtin_amdgcn_permlane32_swap(q0a, q1a, false, false);
      auto r13a = __builtin_amdgcn_permlane32_swap(q0b, q1b, false, false);
      auto r02b = __builtin_amdgcn_permlane32_swap(q2a, q3a, false, false);
      auto r13b = __builtin_amdgcn_permlane32_swap(q2b, q3b, false, false);
      u32x4 u0 = {(u32)r02a[0], (u32)r13a[0], (u32)r02a[1], (u32)r13a[1]};
      u32x4 u1 = {(u32)r02b[0], (u32)r13b[0], (u32)r02b[1], (u32)r13b[1]};
      bf16x8 ap0 = __builtin_bit_cast(bf16x8, u0);          // consumed in-register
      bf16x8 ap1 = __builtin_bit_cast(bf16x8, u1);

#pragma unroll
      for (int cg = 0; cg < 4; ++cg) {
        o[cg][qh] = __builtin_amdgcn_mfma_f32_32x32x16_bf16(ap0, ha[cg], o[cg][qh], 0, 0, 0);
        o[cg][qh] = __builtin_amdgcn_mfma_f32_32x32x16_bf16(ap1, hb[cg], o[cg][qh], 0, 0, 0);
      }
    }

    af0 = naf0; af1 = naf1;
  }

  // ---- one-time kw-combine: bf16-packed partials through LDS ----
  lsh[kw][0][lan] = l2[0];
  lsh[kw][1][lan] = l2[1];
#pragma unroll
  for (int cgp = 0; cgp < 2; ++cgp)
#pragma unroll
    for (int qh = 0; qh < 2; ++qh)
#pragma unroll
      for (int r = 0; r < 16; ++r)
        pls[kw][cgp][qh][r][lan] = pk2(o[cgp * 2][qh][r], o[cgp * 2 + 1][qh][r]);
  __syncthreads();

  const int cgp = kw >> 1, qh = kw & 1;         // this wave's output slice
  float e0[16], e1[16];
#pragma unroll
  for (int r = 0; r < 16; ++r) { e0[r] = 0.f; e1[r] = 0.f; }
#pragma unroll
  for (int kk = 0; kk < 4; ++kk)
#pragma unroll
    for (int r = 0; r < 16; ++r) {
      u32 v = pls[kk][cgp][qh][r][lan];
      e0[r] += __builtin_bit_cast(float, v << 16);
      e1[r] += __builtin_bit_cast(float, v & 0xFFFF0000u);
    }
  const float l_tot = lsh[0][qh][lan] + lsh[1][qh][lan]
                    + lsh[2][qh][lan] + lsh[3][qh][lan];
  const float gi = gamma / l_tot;
#pragma unroll
  for (int r = 0; r < 16; ++r) {
    const int nl = (r & 3) + 8 * (r >> 2) + 4 * g2;
    const float gir = __shfl(gi, nl);
    const size_t row = (size_t)b * NSEQ + n0 + qh * 32 + nl;
    const size_t i0 = row * CDIM + cb * 128 + cgp * 64 + lan31;
    out[i0]      = fmaf(gir, e0[r], x[i0]);
    out[i0 + 32] = fmaf(gir, e1[r], x[i0 + 32]);
  }
}

extern "C" void kernel_launch(void* const* d_in, const int* in_sizes, int n_in,
                              void* d_out, int out_size, void* d_ws, size_t ws_size,
                              hipStream_t stream) {
  const float* x     = (const float*)d_in[0];
  const float* Wf    = (const float*)d_in[1];
  const float* bf    = (const float*)d_in[2];
  const float* Wg    = (const float*)d_in[3];
  const float* bg    = (const float*)d_in[4];
  const float* Wh    = (const float*)d_in[5];
  const float* bh    = (const float*)d_in[6];
  const float* gamma = (const float*)d_in[7];
  float* out = (float*)d_out;

  // layout: hP | fP | g | wfT | wgT | whT  (fP before g so f-prefetch overrun lands in g)
  u16* hP   = (u16*)d_ws;                                    // 8 MB
  u16* fPp  = hP  + (size_t)BATCH * CDIM * NSEQ;             // 1 MB
  u16* g_ws = fPp + (size_t)BATCH * NSEQ * CQK;              // 1 MB
  u16* wfT  = g_ws + (size_t)BATCH * NSEQ * CQK;             // 16 KB
  u16* wgT  = wfT + (size_t)CQK * CDIM;                      // 16 KB
  u16* whT  = wgT + (size_t)CQK * CDIM;                      // 128 KB

  hipLaunchKernelGGL(prep_kernel, dim3(320), dim3(64), 0, stream,
                     Wf, Wg, Wh, wfT, wgT, whT);
  hipLaunchKernelGGL(proj_kernel, dim3(512), dim3(256), 0, stream,
                     x, bf, bg, bh, wfT, wgT, whT, fPp, g_ws, hP);
  hipLaunchKernelGGL(attn_kernel, dim3(512), dim3(256), 0, stream,
                     x, gamma, fPp, g_ws, hP, out);
}

// Round 27
// 77.736 us; speedup vs baseline: 1.1614x; 1.0347x over previous
//
#include <hip/hip_runtime.h>
#include <hip/hip_bf16.h>

#define BATCH 4
#define NSEQ  4096
#define CDIM  256
#define CQK   32
#define L2E   1.44269504088896340736f

typedef short bf16x8 __attribute__((ext_vector_type(8)));   // 8 bf16 in 4 VGPRs
typedef float f32x16 __attribute__((ext_vector_type(16)));
typedef unsigned short u16;
typedef unsigned int   u32;
typedef unsigned int   u32x4 __attribute__((ext_vector_type(4)));

__device__ __forceinline__ u32 pk2(float lo, float hi) {    // v_cvt_pk_bf16_f32
  u16 a = __builtin_bit_cast(u16, __float2bfloat16(lo));
  u16 b = __builtin_bit_cast(u16, __float2bfloat16(hi));
  return (u32)a | ((u32)b << 16);
}
__device__ __forceinline__ bf16x8 ld8(const u16* p) {
  uint4 u = *(const uint4*)p;
  return __builtin_bit_cast(bf16x8, u);
}
// raw v_exp_f32 via builtin (hazard-safe; inline-asm version failed r9 at absmax 2.69)
__device__ __forceinline__ float exp2_raw(float x) {
#if __has_builtin(__builtin_amdgcn_exp2f)
  return __builtin_amdgcn_exp2f(x);
#else
  return exp2f(x);
#endif
}

// ---------------- weight prep -> FRAGMENT-PACKED weights (r27) --------------------------
// wfP/wgP[ks(16)][lane(64)][8]: B-frag tiles for the f/g MFMA (lane l: col=l&31,
//   k=ks*16+(l>>5)*8+j). wfP pre-scaled by L2E.
// whP[cg(8)][ks(16)][lane(64)][8]: A-frag tiles for the h MFMA (lane l: row=c=l&31
//   within group, k=ks*16+(l>>5)*8+j).
// Fragments are element-identical to the old gathered loads -> proj math is bit-exact;
// proj's weight loads become coalesced lane*16B (the old layout was a 32-line gather
// per ld8 — the same line-touch tax that cost attn 3 rounds, r11-r15).
__global__ __launch_bounds__(64) void prep_kernel(
    const float* __restrict__ Wf, const float* __restrict__ Wg, const float* __restrict__ Wh,
    u16* __restrict__ wfP, u16* __restrict__ wgP, u16* __restrict__ whP) {
  const int bid = blockIdx.x, l = threadIdx.x;
  const int c31 = l & 31, kh = l >> 5;
  if (bid < 32) {               // wf (0..15) / wg (16..31), tile = ks
    const bool isg = bid >= 16;
    const int ks = bid & 15;
    const float* W = isg ? Wg : Wf;
    const float scale = isg ? 1.0f : L2E;
    u16* dst = (isg ? wgP : wfP) + (size_t)(ks * 64 + l) * 8;
#pragma unroll
    for (int j = 0; j < 8; ++j) {
      const int k = ks * 16 + kh * 8 + j;
      dst[j] = (u16)(pk2(W[k * CQK + c31] * scale, 0.f) & 0xFFFF);
    }
  } else {                      // wh: tile = (cg, ks)
    const int t  = bid - 32;    // 0..127
    const int cg = t >> 4, ks = t & 15;
    u16* dst = whP + (size_t)((cg * 16 + ks) * 64 + l) * 8;
#pragma unroll
    for (int j = 0; j < 8; ++j) {
      const int k = ks * 16 + kh * 8 + j;
      dst[j] = (u16)(pk2(Wh[k * CDIM + cg * 32 + c31], 0.f) & 0xFFFF);
    }
  }
}

// ---------------- MFMA projection -> FRAGMENT-PACKED outputs ----------------------------
// grid 512 (32 rows/block), 4 waves split work: w0: f+h{0,1}, w1: g+h{2,3},
// w2: h{4,5}, w3: h{6,7}. launch_bounds(256,2) -> 2 waves/SIMD. All weight loads now
// coalesced (lan*16B) from the packed tiles.
// fP[b*128+kc][ks(2)][lane(64)][8]  : A-frag tiles for QK   (kc = 32-key chunk)
// hP[(b*8+cg)*128+kc][ks(2)][lane(64)][8] : B-frag tiles for PV (cg = 32-ch group)
__global__ __launch_bounds__(256, 2) void proj_kernel(
    const float* __restrict__ x,
    const float* __restrict__ bfv, const float* __restrict__ bgv, const float* __restrict__ bhv,
    const u16* __restrict__ wfP, const u16* __restrict__ wgP, const u16* __restrict__ whP,
    u16* __restrict__ fP, u16* __restrict__ g_ws, u16* __restrict__ hP) {
  const int tid   = threadIdx.x;
  const int lan   = tid & 63;
  const int lan31 = lan & 31;
  const int g2    = lan >> 5;
  const int w     = tid >> 6;                   // wave 0..3
  const int row0  = blockIdx.x * 32;            // 32 rows = one key chunk
  const int b     = row0 >> 12;
  const int kcg   = row0 >> 5;                  // global kc = b*128 + (row0&4095)>>5

  // x fragments (each wave loads the block's 32 rows; redundant but L1/L2-cached)
  bf16x8 xf[16];
  const float* xr = x + ((size_t)row0 + lan31) * CDIM + g2 * 8;
#pragma unroll
  for (int ks = 0; ks < 16; ++ks) {
    float4 a = *(const float4*)(xr + ks * 16);
    float4 c = *(const float4*)(xr + ks * 16 + 4);
    u32x4 u = { pk2(a.x, a.y), pk2(a.z, a.w), pk2(c.x, c.y), pk2(c.z, c.w) };
    xf[ks] = __builtin_bit_cast(bf16x8, u);
  }

  if (w < 2) { // w0: f (packed), w1: g (row-major): D[m=row(key)][n=c]
    const u16*  wP   = w ? wgP : wfP;
    const float bias = w ? bgv[lan31] : bfv[lan31] * L2E;
    f32x16 acc;
#pragma unroll
    for (int r = 0; r < 16; ++r) acc[r] = bias;
#pragma unroll
    for (int ks = 0; ks < 16; ++ks)
      acc = __builtin_amdgcn_mfma_f32_32x32x16_bf16(xf[ks], ld8(wP + ks * 512 + lan * 8),
                                                    acc, 0, 0, 0);
    if (w) {
#pragma unroll
      for (int r = 0; r < 16; ++r) {
        const int row = (r & 3) + 8 * (r >> 2) + 4 * g2;
        g_ws[((size_t)row0 + row) * CQK + lan31] = (u16)(pk2(acc[r], 0.f) & 0xFFFF);
      }
    } else {
      u16* fb = fP + (size_t)kcg * 1024
              + (lan31 >> 4) * 512 + ((lan31 >> 3) & 1) * 256 + (lan31 & 7);
#pragma unroll
      for (int r = 0; r < 16; ++r) {
        const int crow = (r & 3) + 8 * (r >> 2) + 4 * g2;   // key row within chunk
        fb[crow * 8] = (u16)(pk2(acc[r], 0.f) & 0xFFFF);
      }
    }
  }

  // h: wave w handles channel groups {2w, 2w+1}; D[m=c][n=row(key)] via swapped operands
#pragma unroll
  for (int t = 0; t < 2; ++t) {
    const int cg = w * 2 + t;
    const int ct = cg * 32;
    f32x16 acc;
#pragma unroll
    for (int r = 0; r < 16; ++r)
      acc[r] = bhv[ct + (r & 3) + 8 * (r >> 2) + 4 * g2];
    const u16* wP = whP + (size_t)(cg * 16) * 512 + lan * 8;
#pragma unroll
    for (int ks = 0; ks < 16; ++ks)
      acc = __builtin_amdgcn_mfma_f32_32x32x16_bf16(ld8(wP + ks * 512), xf[ks], acc, 0, 0, 0);
    u16* hb = hP + ((size_t)(b * 8 + cg) * 128 + ((row0 & (NSEQ - 1)) >> 5)) * 1024
            + (lan31 >> 4) * 512 + ((lan31 >> 3) & 1) * 256 + (lan31 & 7);
#pragma unroll
    for (int r = 0; r < 16; ++r) {
      const int crow = (r & 3) + 8 * (r >> 2) + 4 * g2;     // channel row within group
      hb[crow * 8] = (u16)(pk2(acc[r], 0.f) & 0xFFFF);
    }
  }
}

// ---------------- flash attention: barrier-free main loop (r22/r24 proven 54.6us) -------
// Grid 512 = 4b x 64 q-tiles(64q) x 2 cb -> 2 independent blocks/CU. Block = 4 waves =
// 4 key-splits; wave (kw): 64q x 128ch x 1024 keys. P consumed in-register; zero in-loop
// barriers/LDS; one-time kw-combine epilogue.
// Measured dead ends from this config: setprio (r23 +10%), owner-rotation (r19 +60%),
// forced 4 waves/SIMD (r20 spill +690%), softmax pipelining (r25 +24%). Cross-block
// wave overlap at 2 blocks/CU IS the latency hiding; register budget (128 acc + ~116
// VGPR ~= 244/256) pins occupancy and unroll depth.
__global__ __launch_bounds__(256, 2) void attn_kernel(
    const float* __restrict__ x, const float* __restrict__ gamma_p,
    const u16* __restrict__ fP, const u16* __restrict__ g_ws,
    const u16* __restrict__ hP, float* __restrict__ out) {
  __shared__ u32   pls[4][2][2][16][64];        // [kw][cgp][qh][r][lane] 64KB combine
  __shared__ float lsh[4][2][64];               // [kw][qh][lane] 2KB

  const int tid   = threadIdx.x;
  const int lan   = tid & 63;
  const int lan31 = lan & 31;
  const int g2    = lan >> 5;
  const int kw    = tid >> 6;                   // wave id = key split 0..3
  const int bid   = blockIdx.x;
  const int xcd   = bid & 7;
  const int b     = xcd >> 1;
  const int inner = bid >> 3;                   // 0..63
  const int cb    = inner & 1;                  // channel block 0/1 (128 ch)
  const int n0    = ((((xcd & 1) << 5) | (inner >> 1))) * 64;

  const float gamma = gamma_p[0];

  // g fragments for both 32-query tiles
  bf16x8 bgM[2][2];
#pragma unroll
  for (int qh = 0; qh < 2; ++qh) {
    const u16* gp = g_ws + ((size_t)b * NSEQ + n0 + qh * 32 + lan31) * CQK + g2 * 8;
    bgM[qh][0] = ld8(gp);
    bgM[qh][1] = ld8(gp + 16);
  }

  f32x16 o[4][2], zfrag;                        // [cg][qh] = 128 acc regs
#pragma unroll
  for (int r = 0; r < 16; ++r) zfrag[r] = 0.f;
#pragma unroll
  for (int cg = 0; cg < 4; ++cg) { o[cg][0] = zfrag; o[cg][1] = zfrag; }
  float l2[2] = {0.f, 0.f};

  const u16*  fpk = fP + (size_t)(b * 128 + kw * 32) * 1024 + lan * 8;
  const u16*  hpk = hP + ((size_t)(b * 8 + cb * 4) * 128 + kw * 32) * 1024 + lan * 8;
  const size_t hcg = (size_t)128 * 1024;        // cg stride in elems

  bf16x8 af0 = ld8(fpk), af1 = ld8(fpk + 512);
  fpk += 1024;

  for (int it = 0; it < 32; ++it) {
    bf16x8 naf0 = ld8(fpk), naf1 = ld8(fpk + 512);          // f prefetch (overrun -> g_ws)
    fpk += 1024;
    bf16x8 ha[4], hb[4];                        // h loads hide under softmax
#pragma unroll
    for (int cg = 0; cg < 4; ++cg) {
      ha[cg] = ld8(hpk + cg * hcg);
      hb[cg] = ld8(hpk + cg * hcg + 512);
    }
    hpk += 1024;

#pragma unroll
    for (int qh = 0; qh < 2; ++qh) {
      f32x16 s = __builtin_amdgcn_mfma_f32_32x32x16_bf16(af0, bgM[qh][0], zfrag, 0, 0, 0);
      s        = __builtin_amdgcn_mfma_f32_32x32x16_bf16(af1, bgM[qh][1], s,     0, 0, 0);

      float pv[16];
#pragma unroll
      for (int r = 0; r < 16; ++r) pv[r] = exp2_raw(s[r]);
      float rs = ((pv[0]+pv[1])+(pv[2]+pv[3])) + ((pv[4]+pv[5])+(pv[6]+pv[7]))
               + ((pv[8]+pv[9])+(pv[10]+pv[11])) + ((pv[12]+pv[13])+(pv[14]+pv[15]));
      auto rr = __builtin_amdgcn_permlane32_swap(__builtin_bit_cast(u32, rs),
                                                 __builtin_bit_cast(u32, rs), false, false);
      l2[qh] += __builtin_bit_cast(float, (u32)rr[0]) + __builtin_bit_cast(float, (u32)rr[1]);

      u32 q0a = pk2(pv[0],pv[1]),   q0b = pk2(pv[2],pv[3]);
      u32 q1a = pk2(pv[4],pv[5]),   q1b = pk2(pv[6],pv[7]);
      u32 q2a = pk2(pv[8],pv[9]),   q2b = pk2(pv[10],pv[11]);
      u32 q3a = pk2(pv[12],pv[13]), q3b = pk2(pv[14],pv[15]);
      auto r02a = __builtin_amdgcn_permlane32_swap(q0a, q1a, false, false);
      auto r13a = __builtin_amdgcn_permlane32_swap(q0b, q1b, false, false);
      auto r02b = __builtin_amdgcn_permlane32_swap(q2a, q3a, false, false);
      auto r13b = __builtin_amdgcn_permlane32_swap(q2b, q3b, false, false);
      u32x4 u0 = {(u32)r02a[0], (u32)r13a[0], (u32)r02a[1], (u32)r13a[1]};
      u32x4 u1 = {(u32)r02b[0], (u32)r13b[0], (u32)r02b[1], (u32)r13b[1]};
      bf16x8 ap0 = __builtin_bit_cast(bf16x8, u0);          // consumed in-register
      bf16x8 ap1 = __builtin_bit_cast(bf16x8, u1);

#pragma unroll
      for (int cg = 0; cg < 4; ++cg) {
        o[cg][qh] = __builtin_amdgcn_mfma_f32_32x32x16_bf16(ap0, ha[cg], o[cg][qh], 0, 0, 0);
        o[cg][qh] = __builtin_amdgcn_mfma_f32_32x32x16_bf16(ap1, hb[cg], o[cg][qh], 0, 0, 0);
      }
    }

    af0 = naf0; af1 = naf1;
  }

  // ---- one-time kw-combine: bf16-packed partials through LDS ----
  lsh[kw][0][lan] = l2[0];
  lsh[kw][1][lan] = l2[1];
#pragma unroll
  for (int cgp = 0; cgp < 2; ++cgp)
#pragma unroll
    for (int qh = 0; qh < 2; ++qh)
#pragma unroll
      for (int r = 0; r < 16; ++r)
        pls[kw][cgp][qh][r][lan] = pk2(o[cgp * 2][qh][r], o[cgp * 2 + 1][qh][r]);
  __syncthreads();

  const int cgp = kw >> 1, qh = kw & 1;         // this wave's output slice
  float e0[16], e1[16];
#pragma unroll
  for (int r = 0; r < 16; ++r) { e0[r] = 0.f; e1[r] = 0.f; }
#pragma unroll
  for (int kk = 0; kk < 4; ++kk)
#pragma unroll
    for (int r = 0; r < 16; ++r) {
      u32 v = pls[kk][cgp][qh][r][lan];
      e0[r] += __builtin_bit_cast(float, v << 16);
      e1[r] += __builtin_bit_cast(float, v & 0xFFFF0000u);
    }
  const float l_tot = lsh[0][qh][lan] + lsh[1][qh][lan]
                    + lsh[2][qh][lan] + lsh[3][qh][lan];
  const float gi = gamma / l_tot;
#pragma unroll
  for (int r = 0; r < 16; ++r) {
    const int nl = (r & 3) + 8 * (r >> 2) + 4 * g2;
    const float gir = __shfl(gi, nl);
    const size_t row = (size_t)b * NSEQ + n0 + qh * 32 + nl;
    const size_t i0 = row * CDIM + cb * 128 + cgp * 64 + lan31;
    out[i0]      = fmaf(gir, e0[r], x[i0]);
    out[i0 + 32] = fmaf(gir, e1[r], x[i0 + 32]);
  }
}

extern "C" void kernel_launch(void* const* d_in, const int* in_sizes, int n_in,
                              void* d_out, int out_size, void* d_ws, size_t ws_size,
                              hipStream_t stream) {
  const float* x     = (const float*)d_in[0];
  const float* Wf    = (const float*)d_in[1];
  const float* bf    = (const float*)d_in[2];
  const float* Wg    = (const float*)d_in[3];
  const float* bg    = (const float*)d_in[4];
  const float* Wh    = (const float*)d_in[5];
  const float* bh    = (const float*)d_in[6];
  const float* gamma = (const float*)d_in[7];
  float* out = (float*)d_out;

  // layout: hP | fP | g | wfP | wgP | whP  (fP before g so f-prefetch overrun lands in g)
  u16* hP   = (u16*)d_ws;                                    // 8 MB
  u16* fPp  = hP  + (size_t)BATCH * CDIM * NSEQ;             // 1 MB
  u16* g_ws = fPp + (size_t)BATCH * NSEQ * CQK;              // 1 MB
  u16* wfP  = g_ws + (size_t)BATCH * NSEQ * CQK;             // 16 KB
  u16* wgP  = wfP + (size_t)CQK * CDIM;                      // 16 KB
  u16* whP  = wgP + (size_t)CQK * CDIM;                      // 128 KB

  hipLaunchKernelGGL(prep_kernel, dim3(160), dim3(64), 0, stream,
                     Wf, Wg, Wh, wfP, wgP, whP);
  hipLaunchKernelGGL(proj_kernel, dim3(512), dim3(256), 0, stream,
                     x, bf, bg, bh, wfP, wgP, whP, fPp, g_ws, hP);
  hipLaunchKernelGGL(attn_kernel, dim3(512), dim3(256), 0, stream,
                     x, gamma, fPp, g_ws, hP, out);
}

// Round 28
// 72.910 us; speedup vs baseline: 1.2383x; 1.0662x over previous
//
#include <hip/hip_runtime.h>
#include <hip/hip_bf16.h>

#define BATCH 4
#define NSEQ  4096
#define CDIM  256
#define CQK   32
#define L2E   1.44269504088896340736f

typedef short bf16x8 __attribute__((ext_vector_type(8)));   // 8 bf16 in 4 VGPRs
typedef float f32x16 __attribute__((ext_vector_type(16)));
typedef unsigned short u16;
typedef unsigned int   u32;
typedef unsigned int   u32x4 __attribute__((ext_vector_type(4)));

__device__ __forceinline__ u32 pk2(float lo, float hi) {    // v_cvt_pk_bf16_f32
  u16 a = __builtin_bit_cast(u16, __float2bfloat16(lo));
  u16 b = __builtin_bit_cast(u16, __float2bfloat16(hi));
  return (u32)a | ((u32)b << 16);
}
__device__ __forceinline__ bf16x8 ld8(const u16* p) {
  uint4 u = *(const uint4*)p;
  return __builtin_bit_cast(bf16x8, u);
}
// raw v_exp_f32 via builtin (hazard-safe; inline-asm version failed r9 at absmax 2.69)
__device__ __forceinline__ float exp2_raw(float x) {
#if __has_builtin(__builtin_amdgcn_exp2f)
  return __builtin_amdgcn_exp2f(x);
#else
  return exp2f(x);
#endif
}

// ---------------- weight prep -> FRAGMENT-PACKED weights (r27 measured-good) ------------
// wfP/wgP[ks(16)][lane(64)][8]: B-frag tiles for the f/g MFMA. wfP pre-scaled by L2E.
// whP[cg(8)][ks(16)][lane(64)][8]: A-frag tiles for the h MFMA.
__global__ __launch_bounds__(64) void prep_kernel(
    const float* __restrict__ Wf, const float* __restrict__ Wg, const float* __restrict__ Wh,
    u16* __restrict__ wfP, u16* __restrict__ wgP, u16* __restrict__ whP) {
  const int bid = blockIdx.x, l = threadIdx.x;
  const int c31 = l & 31, kh = l >> 5;
  if (bid < 32) {               // wf (0..15) / wg (16..31), tile = ks
    const bool isg = bid >= 16;
    const int ks = bid & 15;
    const float* W = isg ? Wg : Wf;
    const float scale = isg ? 1.0f : L2E;
    u16* dst = (isg ? wgP : wfP) + (size_t)(ks * 64 + l) * 8;
#pragma unroll
    for (int j = 0; j < 8; ++j) {
      const int k = ks * 16 + kh * 8 + j;
      dst[j] = (u16)(pk2(W[k * CQK + c31] * scale, 0.f) & 0xFFFF);
    }
  } else {                      // wh: tile = (cg, ks)
    const int t  = bid - 32;    // 0..127
    const int cg = t >> 4, ks = t & 15;
    u16* dst = whP + (size_t)((cg * 16 + ks) * 64 + l) * 8;
#pragma unroll
    for (int j = 0; j < 8; ++j) {
      const int k = ks * 16 + kh * 8 + j;
      dst[j] = (u16)(pk2(Wh[k * CDIM + cg * 32 + c31], 0.f) & 0xFFFF);
    }
  }
}

// ---------------- MFMA projection: LDS-staged x, packed weights, packed outputs ---------
// grid 512 (32 rows/block), 4 waves: w0: f+h{0,1}, w1: g+h{2,3}, w2: h{4,5}, w3: h{6,7}.
// r28: x staged through LDS — block loads its 32 rows (32KB) coalesced ONCE (was: each
// wave gathering the same rows, 32-line touches x4 redundancy). Stride 260 f32 keeps
// 16B alignment and breaks pow-2 bank stride (<=4-way residual).
// fP[b*128+kc][ks(2)][lane(64)][8]  : A-frag tiles for QK   (kc = 32-key chunk)
// hP[(b*8+cg)*128+kc][ks(2)][lane(64)][8] : B-frag tiles for PV (cg = 32-ch group)
__global__ __launch_bounds__(256, 2) void proj_kernel(
    const float* __restrict__ x,
    const float* __restrict__ bfv, const float* __restrict__ bgv, const float* __restrict__ bhv,
    const u16* __restrict__ wfP, const u16* __restrict__ wgP, const u16* __restrict__ whP,
    u16* __restrict__ fP, u16* __restrict__ g_ws, u16* __restrict__ hP) {
  __shared__ float xs[32][260];                 // +4 pad: 16B-aligned rows, bank-spread
  const int tid   = threadIdx.x;
  const int lan   = tid & 63;
  const int lan31 = lan & 31;
  const int g2    = lan >> 5;
  const int w     = tid >> 6;                   // wave 0..3
  const int row0  = blockIdx.x * 32;            // 32 rows = one key chunk
  const int b     = row0 >> 12;
  const int kcg   = row0 >> 5;                  // global kc = b*128 + (row0&4095)>>5

  { // cooperative coalesced stage: 2048 float4s, 256 threads x 8 iters (4KB/instr)
    const float4* xg = (const float4*)(x + (size_t)row0 * CDIM);
#pragma unroll
    for (int j = 0; j < 8; ++j) {
      const int idx = j * 256 + tid;            // float4 index in the 32x256 tile
      const int row = idx >> 6, c4 = idx & 63;
      *(float4*)&xs[row][c4 * 4] = xg[idx];
    }
  }
  __syncthreads();

  // per-wave x fragments from LDS
  bf16x8 xf[16];
#pragma unroll
  for (int ks = 0; ks < 16; ++ks) {
    float4 a = *(const float4*)&xs[lan31][ks * 16 + g2 * 8];
    float4 c = *(const float4*)&xs[lan31][ks * 16 + g2 * 8 + 4];
    u32x4 u = { pk2(a.x, a.y), pk2(a.z, a.w), pk2(c.x, c.y), pk2(c.z, c.w) };
    xf[ks] = __builtin_bit_cast(bf16x8, u);
  }

  if (w < 2) { // w0: f (packed), w1: g (row-major): D[m=row(key)][n=c]
    const u16*  wP   = w ? wgP : wfP;
    const float bias = w ? bgv[lan31] : bfv[lan31] * L2E;
    f32x16 acc;
#pragma unroll
    for (int r = 0; r < 16; ++r) acc[r] = bias;
#pragma unroll
    for (int ks = 0; ks < 16; ++ks)
      acc = __builtin_amdgcn_mfma_f32_32x32x16_bf16(xf[ks], ld8(wP + ks * 512 + lan * 8),
                                                    acc, 0, 0, 0);
    if (w) {
#pragma unroll
      for (int r = 0; r < 16; ++r) {
        const int row = (r & 3) + 8 * (r >> 2) + 4 * g2;
        g_ws[((size_t)row0 + row) * CQK + lan31] = (u16)(pk2(acc[r], 0.f) & 0xFFFF);
      }
    } else {
      u16* fb = fP + (size_t)kcg * 1024
              + (lan31 >> 4) * 512 + ((lan31 >> 3) & 1) * 256 + (lan31 & 7);
#pragma unroll
      for (int r = 0; r < 16; ++r) {
        const int crow = (r & 3) + 8 * (r >> 2) + 4 * g2;   // key row within chunk
        fb[crow * 8] = (u16)(pk2(acc[r], 0.f) & 0xFFFF);
      }
    }
  }

  // h: wave w handles channel groups {2w, 2w+1}; D[m=c][n=row(key)] via swapped operands
#pragma unroll
  for (int t = 0; t < 2; ++t) {
    const int cg = w * 2 + t;
    const int ct = cg * 32;
    f32x16 acc;
#pragma unroll
    for (int r = 0; r < 16; ++r)
      acc[r] = bhv[ct + (r & 3) + 8 * (r >> 2) + 4 * g2];
    const u16* wP = whP + (size_t)(cg * 16) * 512 + lan * 8;
#pragma unroll
    for (int ks = 0; ks < 16; ++ks)
      acc = __builtin_amdgcn_mfma_f32_32x32x16_bf16(ld8(wP + ks * 512), xf[ks], acc, 0, 0, 0);
    u16* hb = hP + ((size_t)(b * 8 + cg) * 128 + ((row0 & (NSEQ - 1)) >> 5)) * 1024
            + (lan31 >> 4) * 512 + ((lan31 >> 3) & 1) * 256 + (lan31 & 7);
#pragma unroll
    for (int r = 0; r < 16; ++r) {
      const int crow = (r & 3) + 8 * (r >> 2) + 4 * g2;     // channel row within group
      hb[crow * 8] = (u16)(pk2(acc[r], 0.f) & 0xFFFF);
    }
  }
}

// ---------------- flash attention: barrier-free main loop (r22/r24 proven 54.6us) -------
// Grid 512 = 4b x 64 q-tiles(64q) x 2 cb -> 2 independent blocks/CU. Block = 4 waves =
// 4 key-splits; wave (kw): 64q x 128ch x 1024 keys. P consumed in-register; zero in-loop
// barriers/LDS; one-time kw-combine epilogue.
// Measured dead ends from this config: setprio (r23 +10%), owner-rotation (r19 +60%),
// forced 4 waves/SIMD (r20 spill +690%), softmax pipelining (r25 +24%). Cross-block
// wave overlap at 2 blocks/CU IS the latency hiding; register budget (128 acc + ~116
// VGPR ~= 244/256) pins occupancy and unroll depth.
__global__ __launch_bounds__(256, 2) void attn_kernel(
    const float* __restrict__ x, const float* __restrict__ gamma_p,
    const u16* __restrict__ fP, const u16* __restrict__ g_ws,
    const u16* __restrict__ hP, float* __restrict__ out) {
  __shared__ u32   pls[4][2][2][16][64];        // [kw][cgp][qh][r][lane] 64KB combine
  __shared__ float lsh[4][2][64];               // [kw][qh][lane] 2KB

  const int tid   = threadIdx.x;
  const int lan   = tid & 63;
  const int lan31 = lan & 31;
  const int g2    = lan >> 5;
  const int kw    = tid >> 6;                   // wave id = key split 0..3
  const int bid   = blockIdx.x;
  const int xcd   = bid & 7;
  const int b     = xcd >> 1;
  const int inner = bid >> 3;                   // 0..63
  const int cb    = inner & 1;                  // channel block 0/1 (128 ch)
  const int n0    = ((((xcd & 1) << 5) | (inner >> 1))) * 64;

  const float gamma = gamma_p[0];

  // g fragments for both 32-query tiles
  bf16x8 bgM[2][2];
#pragma unroll
  for (int qh = 0; qh < 2; ++qh) {
    const u16* gp = g_ws + ((size_t)b * NSEQ + n0 + qh * 32 + lan31) * CQK + g2 * 8;
    bgM[qh][0] = ld8(gp);
    bgM[qh][1] = ld8(gp + 16);
  }

  f32x16 o[4][2], zfrag;                        // [cg][qh] = 128 acc regs
#pragma unroll
  for (int r = 0; r < 16; ++r) zfrag[r] = 0.f;
#pragma unroll
  for (int cg = 0; cg < 4; ++cg) { o[cg][0] = zfrag; o[cg][1] = zfrag; }
  float l2[2] = {0.f, 0.f};

  const u16*  fpk = fP + (size_t)(b * 128 + kw * 32) * 1024 + lan * 8;
  const u16*  hpk = hP + ((size_t)(b * 8 + cb * 4) * 128 + kw * 32) * 1024 + lan * 8;
  const size_t hcg = (size_t)128 * 1024;        // cg stride in elems

  bf16x8 af0 = ld8(fpk), af1 = ld8(fpk + 512);
  fpk += 1024;

  for (int it = 0; it < 32; ++it) {
    bf16x8 naf0 = ld8(fpk), naf1 = ld8(fpk + 512);          // f prefetch (overrun -> g_ws)
    fpk += 1024;
    bf16x8 ha[4], hb[4];                        // h loads hide under softmax
#pragma unroll
    for (int cg = 0; cg < 4; ++cg) {
      ha[cg] = ld8(hpk + cg * hcg);
      hb[cg] = ld8(hpk + cg * hcg + 512);
    }
    hpk += 1024;

#pragma unroll
    for (int qh = 0; qh < 2; ++qh) {
      f32x16 s = __builtin_amdgcn_mfma_f32_32x32x16_bf16(af0, bgM[qh][0], zfrag, 0, 0, 0);
      s        = __builtin_amdgcn_mfma_f32_32x32x16_bf16(af1, bgM[qh][1], s,     0, 0, 0);

      float pv[16];
#pragma unroll
      for (int r = 0; r < 16; ++r) pv[r] = exp2_raw(s[r]);
      float rs = ((pv[0]+pv[1])+(pv[2]+pv[3])) + ((pv[4]+pv[5])+(pv[6]+pv[7]))
               + ((pv[8]+pv[9])+(pv[10]+pv[11])) + ((pv[12]+pv[13])+(pv[14]+pv[15]));
      auto rr = __builtin_amdgcn_permlane32_swap(__builtin_bit_cast(u32, rs),
                                                 __builtin_bit_cast(u32, rs), false, false);
      l2[qh] += __builtin_bit_cast(float, (u32)rr[0]) + __builtin_bit_cast(float, (u32)rr[1]);

      u32 q0a = pk2(pv[0],pv[1]),   q0b = pk2(pv[2],pv[3]);
      u32 q1a = pk2(pv[4],pv[5]),   q1b = pk2(pv[6],pv[7]);
      u32 q2a = pk2(pv[8],pv[9]),   q2b = pk2(pv[10],pv[11]);
      u32 q3a = pk2(pv[12],pv[13]), q3b = pk2(pv[14],pv[15]);
      auto r02a = __builtin_amdgcn_permlane32_swap(q0a, q1a, false, false);
      auto r13a = __builtin_amdgcn_permlane32_swap(q0b, q1b, false, false);
      auto r02b = __builtin_amdgcn_permlane32_swap(q2a, q3a, false, false);
      auto r13b = __builtin_amdgcn_permlane32_swap(q2b, q3b, false, false);
      u32x4 u0 = {(u32)r02a[0], (u32)r13a[0], (u32)r02a[1], (u32)r13a[1]};
      u32x4 u1 = {(u32)r02b[0], (u32)r13b[0], (u32)r02b[1], (u32)r13b[1]};
      bf16x8 ap0 = __builtin_bit_cast(bf16x8, u0);          // consumed in-register
      bf16x8 ap1 = __builtin_bit_cast(bf16x8, u1);

#pragma unroll
      for (int cg = 0; cg < 4; ++cg) {
        o[cg][qh] = __builtin_amdgcn_mfma_f32_32x32x16_bf16(ap0, ha[cg], o[cg][qh], 0, 0, 0);
        o[cg][qh] = __builtin_amdgcn_mfma_f32_32x32x16_bf16(ap1, hb[cg], o[cg][qh], 0, 0, 0);
      }
    }

    af0 = naf0; af1 = naf1;
  }

  // ---- one-time kw-combine: bf16-packed partials through LDS ----
  lsh[kw][0][lan] = l2[0];
  lsh[kw][1][lan] = l2[1];
#pragma unroll
  for (int cgp = 0; cgp < 2; ++cgp)
#pragma unroll
    for (int qh = 0; qh < 2; ++qh)
#pragma unroll
      for (int r = 0; r < 16; ++r)
        pls[kw][cgp][qh][r][lan] = pk2(o[cgp * 2][qh][r], o[cgp * 2 + 1][qh][r]);
  __syncthreads();

  const int cgp = kw >> 1, qh = kw & 1;         // this wave's output slice
  float e0[16], e1[16];
#pragma unroll
  for (int r = 0; r < 16; ++r) { e0[r] = 0.f; e1[r] = 0.f; }
#pragma unroll
  for (int kk = 0; kk < 4; ++kk)
#pragma unroll
    for (int r = 0; r < 16; ++r) {
      u32 v = pls[kk][cgp][qh][r][lan];
      e0[r] += __builtin_bit_cast(float, v << 16);
      e1[r] += __builtin_bit_cast(float, v & 0xFFFF0000u);
    }
  const float l_tot = lsh[0][qh][lan] + lsh[1][qh][lan]
                    + lsh[2][qh][lan] + lsh[3][qh][lan];
  const float gi = gamma / l_tot;
#pragma unroll
  for (int r = 0; r < 16; ++r) {
    const int nl = (r & 3) + 8 * (r >> 2) + 4 * g2;
    const float gir = __shfl(gi, nl);
    const size_t row = (size_t)b * NSEQ + n0 + qh * 32 + nl;
    const size_t i0 = row * CDIM + cb * 128 + cgp * 64 + lan31;
    out[i0]      = fmaf(gir, e0[r], x[i0]);
    out[i0 + 32] = fmaf(gir, e1[r], x[i0 + 32]);
  }
}

extern "C" void kernel_launch(void* const* d_in, const int* in_sizes, int n_in,
                              void* d_out, int out_size, void* d_ws, size_t ws_size,
                              hipStream_t stream) {
  const float* x     = (const float*)d_in[0];
  const float* Wf    = (const float*)d_in[1];
  const float* bf    = (const float*)d_in[2];
  const float* Wg    = (const float*)d_in[3];
  const float* bg    = (const float*)d_in[4];
  const float* Wh    = (const float*)d_in[5];
  const float* bh    = (const float*)d_in[6];
  const float* gamma = (const float*)d_in[7];
  float* out = (float*)d_out;

  // layout: hP | fP | g | wfP | wgP | whP  (fP before g so f-prefetch overrun lands in g)
  u16* hP   = (u16*)d_ws;                                    // 8 MB
  u16* fPp  = hP  + (size_t)BATCH * CDIM * NSEQ;             // 1 MB
  u16* g_ws = fPp + (size_t)BATCH * NSEQ * CQK;              // 1 MB
  u16* wfP  = g_ws + (size_t)BATCH * NSEQ * CQK;             // 16 KB
  u16* wgP  = wfP + (size_t)CQK * CDIM;                      // 16 KB
  u16* whP  = wgP + (size_t)CQK * CDIM;                      // 128 KB

  hipLaunchKernelGGL(prep_kernel, dim3(160), dim3(64), 0, stream,
                     Wf, Wg, Wh, wfP, wgP, whP);
  hipLaunchKernelGGL(proj_kernel, dim3(512), dim3(256), 0, stream,
                     x, bf, bg, bh, wfP, wgP, whP, fPp, g_ws, hP);
  hipLaunchKernelGGL(attn_kernel, dim3(512), dim3(256), 0, stream,
                     x, gamma, fPp, g_ws, hP, out);
}

// Round 29
// 70.367 us; speedup vs baseline: 1.2830x; 1.0361x over previous
//
#include <hip/hip_runtime.h>
#include <hip/hip_bf16.h>

#define BATCH 4
#define NSEQ  4096
#define CDIM  256
#define CQK   32
#define L2E   1.44269504088896340736f

typedef short bf16x8 __attribute__((ext_vector_type(8)));   // 8 bf16 in 4 VGPRs
typedef float f32x16 __attribute__((ext_vector_type(16)));
typedef unsigned short u16;
typedef unsigned int   u32;
typedef unsigned int   u32x4 __attribute__((ext_vector_type(4)));

__device__ __forceinline__ u32 pk2(float lo, float hi) {    // v_cvt_pk_bf16_f32
  u16 a = __builtin_bit_cast(u16, __float2bfloat16(lo));
  u16 b = __builtin_bit_cast(u16, __float2bfloat16(hi));
  return (u32)a | ((u32)b << 16);
}
__device__ __forceinline__ bf16x8 ld8(const u16* p) {
  uint4 u = *(const uint4*)p;
  return __builtin_bit_cast(bf16x8, u);
}
// raw v_exp_f32 via builtin (hazard-safe; inline-asm version failed r9 at absmax 2.69)
__device__ __forceinline__ float exp2_raw(float x) {
#if __has_builtin(__builtin_amdgcn_exp2f)
  return __builtin_amdgcn_exp2f(x);
#else
  return exp2f(x);
#endif
}

// D-frag (regs=m, lane=n) -> fragment-of-transpose (lane holds n-row, j-slots=m), the
// attn-verified pk2+permlane pack. u0 = m in [0,16) (ks=0), u1 = m in [16,32) (ks=1).
__device__ __forceinline__ void dpack(const f32x16& acc, u32x4& u0, u32x4& u1) {
  u32 q0a = pk2(acc[0],acc[1]),   q0b = pk2(acc[2],acc[3]);
  u32 q1a = pk2(acc[4],acc[5]),   q1b = pk2(acc[6],acc[7]);
  u32 q2a = pk2(acc[8],acc[9]),   q2b = pk2(acc[10],acc[11]);
  u32 q3a = pk2(acc[12],acc[13]), q3b = pk2(acc[14],acc[15]);
  auto r02a = __builtin_amdgcn_permlane32_swap(q0a, q1a, false, false);
  auto r13a = __builtin_amdgcn_permlane32_swap(q0b, q1b, false, false);
  auto r02b = __builtin_amdgcn_permlane32_swap(q2a, q3a, false, false);
  auto r13b = __builtin_amdgcn_permlane32_swap(q2b, q3b, false, false);
  u0 = u32x4{(u32)r02a[0], (u32)r13a[0], (u32)r02a[1], (u32)r13a[1]};
  u1 = u32x4{(u32)r02b[0], (u32)r13b[0], (u32)r02b[1], (u32)r13b[1]};
}

// ---------------- weight prep -> FRAGMENT-PACKED weights (r27 measured-good) ------------
// wfP/wgP[ks(16)][lane(64)][8]; whP[cg(8)][ks(16)][lane(64)][8]. Same bytes serve as
// A- or B-operand fragments (layout duality). wfP pre-scaled by L2E.
__global__ __launch_bounds__(64) void prep_kernel(
    const float* __restrict__ Wf, const float* __restrict__ Wg, const float* __restrict__ Wh,
    u16* __restrict__ wfP, u16* __restrict__ wgP, u16* __restrict__ whP) {
  const int bid = blockIdx.x, l = threadIdx.x;
  const int c31 = l & 31, kh = l >> 5;
  if (bid < 32) {               // wf (0..15) / wg (16..31), tile = ks
    const bool isg = bid >= 16;
    const int ks = bid & 15;
    const float* W = isg ? Wg : Wf;
    const float scale = isg ? 1.0f : L2E;
    u16* dst = (isg ? wgP : wfP) + (size_t)(ks * 64 + l) * 8;
#pragma unroll
    for (int j = 0; j < 8; ++j) {
      const int k = ks * 16 + kh * 8 + j;
      dst[j] = (u16)(pk2(W[k * CQK + c31] * scale, 0.f) & 0xFFFF);
    }
  } else {                      // wh: tile = (cg, ks)
    const int t  = bid - 32;    // 0..127
    const int cg = t >> 4, ks = t & 15;
    u16* dst = whP + (size_t)((cg * 16 + ks) * 64 + l) * 8;
#pragma unroll
    for (int j = 0; j < 8; ++j) {
      const int k = ks * 16 + kh * 8 + j;
      dst[j] = (u16)(pk2(Wh[k * CDIM + cg * 32 + c31], 0.f) & 0xFFFF);
    }
  }
}

// ---------------- MFMA projection: LDS-staged x, in-register transpose, coalesced st ----
// grid 512 (32 rows/block), 4 waves: w0: f+h{0,1}, w1: g+h{2,3}, w2: h{4,5}, w3: h{6,7}.
// r29: f and h computed with SWAPPED operands so D = transpose of the output tile, then
// dpack() (attn's verified pk2+permlane transform) yields the fragment in-register ->
// 2 coalesced 16B/lane stores per tile (was 16 scatter u16 stores). Bit-identical values.
// fP[b*128+kc][ks(2)][lane(64)][8]  : A-frag tiles for QK   (kc = 32-key chunk)
// hP[(b*8+cg)*128+kc][ks(2)][lane(64)][8] : B-frag tiles for PV (cg = 32-ch group)
__global__ __launch_bounds__(256, 2) void proj_kernel(
    const float* __restrict__ x,
    const float* __restrict__ bfv, const float* __restrict__ bgv, const float* __restrict__ bhv,
    const u16* __restrict__ wfP, const u16* __restrict__ wgP, const u16* __restrict__ whP,
    u16* __restrict__ fP, u16* __restrict__ g_ws, u16* __restrict__ hP) {
  __shared__ float xs[32][260];                 // +4 pad: 16B-aligned rows, bank-spread
  const int tid   = threadIdx.x;
  const int lan   = tid & 63;
  const int lan31 = lan & 31;
  const int g2    = lan >> 5;
  const int w     = tid >> 6;                   // wave 0..3
  const int row0  = blockIdx.x * 32;            // 32 rows = one key chunk
  const int b     = row0 >> 12;
  const int kcg   = row0 >> 5;                  // global kc = b*128 + (row0&4095)>>5

  { // cooperative coalesced stage: 2048 float4s, 256 threads x 8 iters (4KB/instr)
    const float4* xg = (const float4*)(x + (size_t)row0 * CDIM);
#pragma unroll
    for (int j = 0; j < 8; ++j) {
      const int idx = j * 256 + tid;            // float4 index in the 32x256 tile
      const int row = idx >> 6, c4 = idx & 63;
      *(float4*)&xs[row][c4 * 4] = xg[idx];
    }
  }
  __syncthreads();

  // per-wave x fragments from LDS (serve as A: row=xrow, or B: col=xrow — same bytes)
  bf16x8 xf[16];
#pragma unroll
  for (int ks = 0; ks < 16; ++ks) {
    float4 a = *(const float4*)&xs[lan31][ks * 16 + g2 * 8];
    float4 c = *(const float4*)&xs[lan31][ks * 16 + g2 * 8 + 4];
    u32x4 u = { pk2(a.x, a.y), pk2(a.z, a.w), pk2(c.x, c.y), pk2(c.z, c.w) };
    xf[ks] = __builtin_bit_cast(bf16x8, u);
  }

  if (w == 0) { // f: D[m=c][n=key] via (wfP as A, xf as B); dpack -> fP tile in-register
    f32x16 acc;
#pragma unroll
    for (int r = 0; r < 16; ++r)
      acc[r] = bfv[(r & 3) + 8 * (r >> 2) + 4 * g2] * L2E;  // bias per m=c (reg index)
#pragma unroll
    for (int ks = 0; ks < 16; ++ks)
      acc = __builtin_amdgcn_mfma_f32_32x32x16_bf16(ld8(wfP + ks * 512 + lan * 8), xf[ks],
                                                    acc, 0, 0, 0);
    u32x4 u0, u1;
    dpack(acc, u0, u1);                         // lane=key-row, j=c
    u16* fb = fP + (size_t)kcg * 1024 + lan * 8;
    *(uint4*)fb         = __builtin_bit_cast(uint4, u0);    // c 0..15  (ks=0)
    *(uint4*)(fb + 512) = __builtin_bit_cast(uint4, u1);    // c 16..31 (ks=1)
  } else if (w == 1) { // g: row-major (unchanged path): D[m=key][n=c]
    f32x16 acc;
#pragma unroll
    for (int r = 0; r < 16; ++r) acc[r] = bgv[lan31];
#pragma unroll
    for (int ks = 0; ks < 16; ++ks)
      acc = __builtin_amdgcn_mfma_f32_32x32x16_bf16(xf[ks], ld8(wgP + ks * 512 + lan * 8),
                                                    acc, 0, 0, 0);
#pragma unroll
    for (int r = 0; r < 16; ++r) {
      const int row = (r & 3) + 8 * (r >> 2) + 4 * g2;
      g_ws[((size_t)row0 + row) * CQK + lan31] = (u16)(pk2(acc[r], 0.f) & 0xFFFF);
    }
  }

  // h: wave w handles channel groups {2w, 2w+1}; D[m=key][n=c] via (xf as A, whP as B);
  // dpack -> hP B-frag tile (lane=c, j=key) stored coalesced.
#pragma unroll
  for (int t = 0; t < 2; ++t) {
    const int cg = w * 2 + t;
    const int ct = cg * 32;
    f32x16 acc;
#pragma unroll
    for (int r = 0; r < 16; ++r) acc[r] = bhv[ct + lan31];  // bias per n=c (lane)
    const u16* wP = whP + (size_t)(cg * 16) * 512 + lan * 8;
#pragma unroll
    for (int ks = 0; ks < 16; ++ks)
      acc = __builtin_amdgcn_mfma_f32_32x32x16_bf16(xf[ks], ld8(wP + ks * 512), acc, 0, 0, 0);
    u32x4 u0, u1;
    dpack(acc, u0, u1);                         // lane=c, j=key
    u16* hb = hP + ((size_t)(b * 8 + cg) * 128 + ((row0 & (NSEQ - 1)) >> 5)) * 1024 + lan * 8;
    *(uint4*)hb         = __builtin_bit_cast(uint4, u0);    // keys 0..15  (ks=0)
    *(uint4*)(hb + 512) = __builtin_bit_cast(uint4, u1);    // keys 16..31 (ks=1)
  }
}

// ---------------- flash attention: barrier-free main loop (r22/r24 proven 54.6us) -------
// Grid 512 = 4b x 64 q-tiles(64q) x 2 cb -> 2 independent blocks/CU. Block = 4 waves =
// 4 key-splits; wave (kw): 64q x 128ch x 1024 keys. P consumed in-register; zero in-loop
// barriers/LDS; one-time kw-combine epilogue.
// Measured dead ends from this config: setprio (r23 +10%), owner-rotation (r19 +60%),
// forced 4 waves/SIMD (r20 spill +690%), softmax pipelining (r25 +24%). Cross-block
// wave overlap at 2 blocks/CU IS the latency hiding; register budget (128 acc + ~116
// VGPR ~= 244/256) pins occupancy and unroll depth.
__global__ __launch_bounds__(256, 2) void attn_kernel(
    const float* __restrict__ x, const float* __restrict__ gamma_p,
    const u16* __restrict__ fP, const u16* __restrict__ g_ws,
    const u16* __restrict__ hP, float* __restrict__ out) {
  __shared__ u32   pls[4][2][2][16][64];        // [kw][cgp][qh][r][lane] 64KB combine
  __shared__ float lsh[4][2][64];               // [kw][qh][lane] 2KB

  const int tid   = threadIdx.x;
  const int lan   = tid & 63;
  const int lan31 = lan & 31;
  const int g2    = lan >> 5;
  const int kw    = tid >> 6;                   // wave id = key split 0..3
  const int bid   = blockIdx.x;
  const int xcd   = bid & 7;
  const int b     = xcd >> 1;
  const int inner = bid >> 3;                   // 0..63
  const int cb    = inner & 1;                  // channel block 0/1 (128 ch)
  const int n0    = ((((xcd & 1) << 5) | (inner >> 1))) * 64;

  const float gamma = gamma_p[0];

  // g fragments for both 32-query tiles
  bf16x8 bgM[2][2];
#pragma unroll
  for (int qh = 0; qh < 2; ++qh) {
    const u16* gp = g_ws + ((size_t)b * NSEQ + n0 + qh * 32 + lan31) * CQK + g2 * 8;
    bgM[qh][0] = ld8(gp);
    bgM[qh][1] = ld8(gp + 16);
  }

  f32x16 o[4][2], zfrag;                        // [cg][qh] = 128 acc regs
#pragma unroll
  for (int r = 0; r < 16; ++r) zfrag[r] = 0.f;
#pragma unroll
  for (int cg = 0; cg < 4; ++cg) { o[cg][0] = zfrag; o[cg][1] = zfrag; }
  float l2[2] = {0.f, 0.f};

  const u16*  fpk = fP + (size_t)(b * 128 + kw * 32) * 1024 + lan * 8;
  const u16*  hpk = hP + ((size_t)(b * 8 + cb * 4) * 128 + kw * 32) * 1024 + lan * 8;
  const size_t hcg = (size_t)128 * 1024;        // cg stride in elems

  bf16x8 af0 = ld8(fpk), af1 = ld8(fpk + 512);
  fpk += 1024;

  for (int it = 0; it < 32; ++it) {
    bf16x8 naf0 = ld8(fpk), naf1 = ld8(fpk + 512);          // f prefetch (overrun -> g_ws)
    fpk += 1024;
    bf16x8 ha[4], hb[4];                        // h loads hide under softmax
#pragma unroll
    for (int cg = 0; cg < 4; ++cg) {
      ha[cg] = ld8(hpk + cg * hcg);
      hb[cg] = ld8(hpk + cg * hcg + 512);
    }
    hpk += 1024;

#pragma unroll
    for (int qh = 0; qh < 2; ++qh) {
      f32x16 s = __builtin_amdgcn_mfma_f32_32x32x16_bf16(af0, bgM[qh][0], zfrag, 0, 0, 0);
      s        = __builtin_amdgcn_mfma_f32_32x32x16_bf16(af1, bgM[qh][1], s,     0, 0, 0);

      float pv[16];
#pragma unroll
      for (int r = 0; r < 16; ++r) pv[r] = exp2_raw(s[r]);
      float rs = ((pv[0]+pv[1])+(pv[2]+pv[3])) + ((pv[4]+pv[5])+(pv[6]+pv[7]))
               + ((pv[8]+pv[9])+(pv[10]+pv[11])) + ((pv[12]+pv[13])+(pv[14]+pv[15]));
      auto rr = __builtin_amdgcn_permlane32_swap(__builtin_bit_cast(u32, rs),
                                                 __builtin_bit_cast(u32, rs), false, false);
      l2[qh] += __builtin_bit_cast(float, (u32)rr[0]) + __builtin_bit_cast(float, (u32)rr[1]);

      f32x16 pvv;
#pragma unroll
      for (int r = 0; r < 16; ++r) pvv[r] = pv[r];
      u32x4 u0, u1;
      dpack(pvv, u0, u1);
      bf16x8 ap0 = __builtin_bit_cast(bf16x8, u0);          // consumed in-register
      bf16x8 ap1 = __builtin_bit_cast(bf16x8, u1);

#pragma unroll
      for (int cg = 0; cg < 4; ++cg) {
        o[cg][qh] = __builtin_amdgcn_mfma_f32_32x32x16_bf16(ap0, ha[cg], o[cg][qh], 0, 0, 0);
        o[cg][qh] = __builtin_amdgcn_mfma_f32_32x32x16_bf16(ap1, hb[cg], o[cg][qh], 0, 0, 0);
      }
    }

    af0 = naf0; af1 = naf1;
  }

  // ---- one-time kw-combine: bf16-packed partials through LDS ----
  lsh[kw][0][lan] = l2[0];
  lsh[kw][1][lan] = l2[1];
#pragma unroll
  for (int cgp = 0; cgp < 2; ++cgp)
#pragma unroll
    for (int qh = 0; qh < 2; ++qh)
#pragma unroll
      for (int r = 0; r < 16; ++r)
        pls[kw][cgp][qh][r][lan] = pk2(o[cgp * 2][qh][r], o[cgp * 2 + 1][qh][r]);
  __syncthreads();

  const int cgp = kw >> 1, qh = kw & 1;         // this wave's output slice
  float e0[16], e1[16];
#pragma unroll
  for (int r = 0; r < 16; ++r) { e0[r] = 0.f; e1[r] = 0.f; }
#pragma unroll
  for (int kk = 0; kk < 4; ++kk)
#pragma unroll
    for (int r = 0; r < 16; ++r) {
      u32 v = pls[kk][cgp][qh][r][lan];
      e0[r] += __builtin_bit_cast(float, v << 16);
      e1[r] += __builtin_bit_cast(float, v & 0xFFFF0000u);
    }
  const float l_tot = lsh[0][qh][lan] + lsh[1][qh][lan]
                    + lsh[2][qh][lan] + lsh[3][qh][lan];
  const float gi = gamma / l_tot;
#pragma unroll
  for (int r = 0; r < 16; ++r) {
    const int nl = (r & 3) + 8 * (r >> 2) + 4 * g2;
    const float gir = __shfl(gi, nl);
    const size_t row = (size_t)b * NSEQ + n0 + qh * 32 + nl;
    const size_t i0 = row * CDIM + cb * 128 + cgp * 64 + lan31;
    out[i0]      = fmaf(gir, e0[r], x[i0]);
    out[i0 + 32] = fmaf(gir, e1[r], x[i0 + 32]);
  }
}

extern "C" void kernel_launch(void* const* d_in, const int* in_sizes, int n_in,
                              void* d_out, int out_size, void* d_ws, size_t ws_size,
                              hipStream_t stream) {
  const float* x     = (const float*)d_in[0];
  const float* Wf    = (const float*)d_in[1];
  const float* bf    = (const float*)d_in[2];
  const float* Wg    = (const float*)d_in[3];
  const float* bg    = (const float*)d_in[4];
  const float* Wh    = (const float*)d_in[5];
  const float* bh    = (const float*)d_in[6];
  const float* gamma = (const float*)d_in[7];
  float* out = (float*)d_out;

  // layout: hP | fP | g | wfP | wgP | whP  (fP before g so f-prefetch overrun lands in g)
  u16* hP   = (u16*)d_ws;                                    // 8 MB
  u16* fPp  = hP  + (size_t)BATCH * CDIM * NSEQ;             // 1 MB
  u16* g_ws = fPp + (size_t)BATCH * NSEQ * CQK;              // 1 MB
  u16* wfP  = g_ws + (size_t)BATCH * NSEQ * CQK;             // 16 KB
  u16* wgP  = wfP + (size_t)CQK * CDIM;                      // 16 KB
  u16* whP  = wgP + (size_t)CQK * CDIM;                      // 128 KB

  hipLaunchKernelGGL(prep_kernel, dim3(160), dim3(64), 0, stream,
                     Wf, Wg, Wh, wfP, wgP, whP);
  hipLaunchKernelGGL(proj_kernel, dim3(512), dim3(256), 0, stream,
                     x, bf, bg, bh, wfP, wgP, whP, fPp, g_ws, hP);
  hipLaunchKernelGGL(attn_kernel, dim3(512), dim3(256), 0, stream,
                     x, gamma, fPp, g_ws, hP, out);
}

// Round 30
// 69.691 us; speedup vs baseline: 1.2955x; 1.0097x over previous
//
#include <hip/hip_runtime.h>
#include <hip/hip_bf16.h>

#define BATCH 4
#define NSEQ  4096
#define CDIM  256
#define CQK   32
#define L2E   1.44269504088896340736f

typedef short bf16x8 __attribute__((ext_vector_type(8)));   // 8 bf16 in 4 VGPRs
typedef float f32x16 __attribute__((ext_vector_type(16)));
typedef unsigned short u16;
typedef unsigned int   u32;
typedef unsigned int   u32x4 __attribute__((ext_vector_type(4)));

__device__ __forceinline__ u32 pk2(float lo, float hi) {    // v_cvt_pk_bf16_f32
  u16 a = __builtin_bit_cast(u16, __float2bfloat16(lo));
  u16 b = __builtin_bit_cast(u16, __float2bfloat16(hi));
  return (u32)a | ((u32)b << 16);
}
__device__ __forceinline__ bf16x8 ld8(const u16* p) {
  uint4 u = *(const uint4*)p;
  return __builtin_bit_cast(bf16x8, u);
}
// raw v_exp_f32 via builtin (hazard-safe; inline-asm version failed r9 at absmax 2.69)
__device__ __forceinline__ float exp2_raw(float x) {
#if __has_builtin(__builtin_amdgcn_exp2f)
  return __builtin_amdgcn_exp2f(x);
#else
  return exp2f(x);
#endif
}

// D-frag (regs=m, lane=n) -> fragment-of-transpose (lane holds n-row, j-slots=m), the
// attn-verified pk2+permlane pack. u0 = m in [0,16) (ks=0), u1 = m in [16,32) (ks=1).
__device__ __forceinline__ void dpack(const f32x16& acc, u32x4& u0, u32x4& u1) {
  u32 q0a = pk2(acc[0],acc[1]),   q0b = pk2(acc[2],acc[3]);
  u32 q1a = pk2(acc[4],acc[5]),   q1b = pk2(acc[6],acc[7]);
  u32 q2a = pk2(acc[8],acc[9]),   q2b = pk2(acc[10],acc[11]);
  u32 q3a = pk2(acc[12],acc[13]), q3b = pk2(acc[14],acc[15]);
  auto r02a = __builtin_amdgcn_permlane32_swap(q0a, q1a, false, false);
  auto r13a = __builtin_amdgcn_permlane32_swap(q0b, q1b, false, false);
  auto r02b = __builtin_amdgcn_permlane32_swap(q2a, q3a, false, false);
  auto r13b = __builtin_amdgcn_permlane32_swap(q2b, q3b, false, false);
  u0 = u32x4{(u32)r02a[0], (u32)r13a[0], (u32)r02a[1], (u32)r13a[1]};
  u1 = u32x4{(u32)r02b[0], (u32)r13b[0], (u32)r02b[1], (u32)r13b[1]};
}

// ---------------- weight prep -> FRAGMENT-PACKED weights (r27 measured-good) ------------
// wfP/wgP[ks(16)][lane(64)][8]; whP[cg(8)][ks(16)][lane(64)][8]. Same bytes serve as
// A- or B-operand fragments (layout duality). wfP pre-scaled by L2E.
__global__ __launch_bounds__(64) void prep_kernel(
    const float* __restrict__ Wf, const float* __restrict__ Wg, const float* __restrict__ Wh,
    u16* __restrict__ wfP, u16* __restrict__ wgP, u16* __restrict__ whP) {
  const int bid = blockIdx.x, l = threadIdx.x;
  const int c31 = l & 31, kh = l >> 5;
  if (bid < 32) {               // wf (0..15) / wg (16..31), tile = ks
    const bool isg = bid >= 16;
    const int ks = bid & 15;
    const float* W = isg ? Wg : Wf;
    const float scale = isg ? 1.0f : L2E;
    u16* dst = (isg ? wgP : wfP) + (size_t)(ks * 64 + l) * 8;
#pragma unroll
    for (int j = 0; j < 8; ++j) {
      const int k = ks * 16 + kh * 8 + j;
      dst[j] = (u16)(pk2(W[k * CQK + c31] * scale, 0.f) & 0xFFFF);
    }
  } else {                      // wh: tile = (cg, ks)
    const int t  = bid - 32;    // 0..127
    const int cg = t >> 4, ks = t & 15;
    u16* dst = whP + (size_t)((cg * 16 + ks) * 64 + l) * 8;
#pragma unroll
    for (int j = 0; j < 8; ++j) {
      const int k = ks * 16 + kh * 8 + j;
      dst[j] = (u16)(pk2(Wh[k * CDIM + cg * 32 + c31], 0.f) & 0xFFFF);
    }
  }
}

// ---------------- MFMA projection: 512-thr blocks (2 key-chunks), 4 waves/SIMD ----------
// r30: grid 256, 8 waves = (chunk 0/1) x (role 0..3). Per-wave work/math/layout identical
// to r29; register footprint (~120) fits the 128 cap -> launch_bounds(512,4) doubles
// latency hiding (proj was 2 waves/SIMD, serial MFMA chains exposed). xs = 64 rows.
// fP[b*128+kc][ks(2)][lane(64)][8]  : A-frag tiles for QK   (kc = 32-key chunk)
// hP[(b*8+cg)*128+kc][ks(2)][lane(64)][8] : B-frag tiles for PV (cg = 32-ch group)
__global__ __launch_bounds__(512, 4) void proj_kernel(
    const float* __restrict__ x,
    const float* __restrict__ bfv, const float* __restrict__ bgv, const float* __restrict__ bhv,
    const u16* __restrict__ wfP, const u16* __restrict__ wgP, const u16* __restrict__ whP,
    u16* __restrict__ fP, u16* __restrict__ g_ws, u16* __restrict__ hP) {
  __shared__ float xs[64][260];                 // +4 pad: 16B-aligned rows, bank-spread
  const int tid   = threadIdx.x;
  const int lan   = tid & 63;
  const int lan31 = lan & 31;
  const int g2    = lan >> 5;
  const int w8    = tid >> 6;                   // wave 0..7
  const int chunk = w8 >> 2;                    // key-chunk within block: 0/1
  const int w     = w8 & 3;                     // role 0..3
  const int row0  = blockIdx.x * 64 + chunk * 32;
  const int b     = row0 >> 12;
  const int kcg   = row0 >> 5;                  // global kc = b*128 + (row0&4095)>>5

  { // cooperative coalesced stage: 4096 float4s, 512 threads x 8 iters (8KB/instr)
    const float4* xg = (const float4*)(x + (size_t)(blockIdx.x * 64) * CDIM);
#pragma unroll
    for (int j = 0; j < 8; ++j) {
      const int idx = j * 512 + tid;            // float4 index in the 64x256 tile
      const int row = idx >> 6, c4 = idx & 63;
      *(float4*)&xs[row][c4 * 4] = xg[idx];
    }
  }
  __syncthreads();

  // per-wave x fragments from LDS (serve as A: row=xrow, or B: col=xrow — same bytes)
  const int xr = chunk * 32 + lan31;
  bf16x8 xf[16];
#pragma unroll
  for (int ks = 0; ks < 16; ++ks) {
    float4 a = *(const float4*)&xs[xr][ks * 16 + g2 * 8];
    float4 c = *(const float4*)&xs[xr][ks * 16 + g2 * 8 + 4];
    u32x4 u = { pk2(a.x, a.y), pk2(a.z, a.w), pk2(c.x, c.y), pk2(c.z, c.w) };
    xf[ks] = __builtin_bit_cast(bf16x8, u);
  }

  if (w == 0) { // f: D[m=c][n=key] via (wfP as A, xf as B); dpack -> fP tile in-register
    f32x16 acc;
#pragma unroll
    for (int r = 0; r < 16; ++r)
      acc[r] = bfv[(r & 3) + 8 * (r >> 2) + 4 * g2] * L2E;  // bias per m=c (reg index)
#pragma unroll
    for (int ks = 0; ks < 16; ++ks)
      acc = __builtin_amdgcn_mfma_f32_32x32x16_bf16(ld8(wfP + ks * 512 + lan * 8), xf[ks],
                                                    acc, 0, 0, 0);
    u32x4 u0, u1;
    dpack(acc, u0, u1);                         // lane=key-row, j=c
    u16* fb = fP + (size_t)kcg * 1024 + lan * 8;
    *(uint4*)fb         = __builtin_bit_cast(uint4, u0);    // c 0..15  (ks=0)
    *(uint4*)(fb + 512) = __builtin_bit_cast(uint4, u1);    // c 16..31 (ks=1)
  } else if (w == 1) { // g: row-major (unchanged path): D[m=key][n=c]
    f32x16 acc;
#pragma unroll
    for (int r = 0; r < 16; ++r) acc[r] = bgv[lan31];
#pragma unroll
    for (int ks = 0; ks < 16; ++ks)
      acc = __builtin_amdgcn_mfma_f32_32x32x16_bf16(xf[ks], ld8(wgP + ks * 512 + lan * 8),
                                                    acc, 0, 0, 0);
#pragma unroll
    for (int r = 0; r < 16; ++r) {
      const int row = (r & 3) + 8 * (r >> 2) + 4 * g2;
      g_ws[((size_t)row0 + row) * CQK + lan31] = (u16)(pk2(acc[r], 0.f) & 0xFFFF);
    }
  }

  // h: role w handles channel groups {2w, 2w+1}; D[m=key][n=c] via (xf as A, whP as B);
  // dpack -> hP B-frag tile (lane=c, j=key) stored coalesced.
#pragma unroll
  for (int t = 0; t < 2; ++t) {
    const int cg = w * 2 + t;
    const int ct = cg * 32;
    f32x16 acc;
#pragma unroll
    for (int r = 0; r < 16; ++r) acc[r] = bhv[ct + lan31];  // bias per n=c (lane)
    const u16* wP = whP + (size_t)(cg * 16) * 512 + lan * 8;
#pragma unroll
    for (int ks = 0; ks < 16; ++ks)
      acc = __builtin_amdgcn_mfma_f32_32x32x16_bf16(xf[ks], ld8(wP + ks * 512), acc, 0, 0, 0);
    u32x4 u0, u1;
    dpack(acc, u0, u1);                         // lane=c, j=key
    u16* hb = hP + ((size_t)(b * 8 + cg) * 128 + ((row0 & (NSEQ - 1)) >> 5)) * 1024 + lan * 8;
    *(uint4*)hb         = __builtin_bit_cast(uint4, u0);    // keys 0..15  (ks=0)
    *(uint4*)(hb + 512) = __builtin_bit_cast(uint4, u1);    // keys 16..31 (ks=1)
  }
}

// ---------------- flash attention: barrier-free main loop (r22/r24 proven 54.6us) -------
// Grid 512 = 4b x 64 q-tiles(64q) x 2 cb -> 2 independent blocks/CU. Block = 4 waves =
// 4 key-splits; wave (kw): 64q x 128ch x 1024 keys. P consumed in-register; zero in-loop
// barriers/LDS; one-time kw-combine epilogue.
// Measured dead ends from this config: setprio (r23 +10%), owner-rotation (r19 +60%),
// forced 4 waves/SIMD (r20 spill +690%), softmax pipelining (r25 +24%). Cross-block
// wave overlap at 2 blocks/CU IS the latency hiding; register budget (128 acc + ~116
// VGPR ~= 244/256) pins occupancy and unroll depth.
__global__ __launch_bounds__(256, 2) void attn_kernel(
    const float* __restrict__ x, const float* __restrict__ gamma_p,
    const u16* __restrict__ fP, const u16* __restrict__ g_ws,
    const u16* __restrict__ hP, float* __restrict__ out) {
  __shared__ u32   pls[4][2][2][16][64];        // [kw][cgp][qh][r][lane] 64KB combine
  __shared__ float lsh[4][2][64];               // [kw][qh][lane] 2KB

  const int tid   = threadIdx.x;
  const int lan   = tid & 63;
  const int lan31 = lan & 31;
  const int g2    = lan >> 5;
  const int kw    = tid >> 6;                   // wave id = key split 0..3
  const int bid   = blockIdx.x;
  const int xcd   = bid & 7;
  const int b     = xcd >> 1;
  const int inner = bid >> 3;                   // 0..63
  const int cb    = inner & 1;                  // channel block 0/1 (128 ch)
  const int n0    = ((((xcd & 1) << 5) | (inner >> 1))) * 64;

  const float gamma = gamma_p[0];

  // g fragments for both 32-query tiles
  bf16x8 bgM[2][2];
#pragma unroll
  for (int qh = 0; qh < 2; ++qh) {
    const u16* gp = g_ws + ((size_t)b * NSEQ + n0 + qh * 32 + lan31) * CQK + g2 * 8;
    bgM[qh][0] = ld8(gp);
    bgM[qh][1] = ld8(gp + 16);
  }

  f32x16 o[4][2], zfrag;                        // [cg][qh] = 128 acc regs
#pragma unroll
  for (int r = 0; r < 16; ++r) zfrag[r] = 0.f;
#pragma unroll
  for (int cg = 0; cg < 4; ++cg) { o[cg][0] = zfrag; o[cg][1] = zfrag; }
  float l2[2] = {0.f, 0.f};

  const u16*  fpk = fP + (size_t)(b * 128 + kw * 32) * 1024 + lan * 8;
  const u16*  hpk = hP + ((size_t)(b * 8 + cb * 4) * 128 + kw * 32) * 1024 + lan * 8;
  const size_t hcg = (size_t)128 * 1024;        // cg stride in elems

  bf16x8 af0 = ld8(fpk), af1 = ld8(fpk + 512);
  fpk += 1024;

  for (int it = 0; it < 32; ++it) {
    bf16x8 naf0 = ld8(fpk), naf1 = ld8(fpk + 512);          // f prefetch (overrun -> g_ws)
    fpk += 1024;
    bf16x8 ha[4], hb[4];                        // h loads hide under softmax
#pragma unroll
    for (int cg = 0; cg < 4; ++cg) {
      ha[cg] = ld8(hpk + cg * hcg);
      hb[cg] = ld8(hpk + cg * hcg + 512);
    }
    hpk += 1024;

#pragma unroll
    for (int qh = 0; qh < 2; ++qh) {
      f32x16 s = __builtin_amdgcn_mfma_f32_32x32x16_bf16(af0, bgM[qh][0], zfrag, 0, 0, 0);
      s        = __builtin_amdgcn_mfma_f32_32x32x16_bf16(af1, bgM[qh][1], s,     0, 0, 0);

      float pv[16];
#pragma unroll
      for (int r = 0; r < 16; ++r) pv[r] = exp2_raw(s[r]);
      float rs = ((pv[0]+pv[1])+(pv[2]+pv[3])) + ((pv[4]+pv[5])+(pv[6]+pv[7]))
               + ((pv[8]+pv[9])+(pv[10]+pv[11])) + ((pv[12]+pv[13])+(pv[14]+pv[15]));
      auto rr = __builtin_amdgcn_permlane32_swap(__builtin_bit_cast(u32, rs),
                                                 __builtin_bit_cast(u32, rs), false, false);
      l2[qh] += __builtin_bit_cast(float, (u32)rr[0]) + __builtin_bit_cast(float, (u32)rr[1]);

      f32x16 pvv;
#pragma unroll
      for (int r = 0; r < 16; ++r) pvv[r] = pv[r];
      u32x4 u0, u1;
      dpack(pvv, u0, u1);
      bf16x8 ap0 = __builtin_bit_cast(bf16x8, u0);          // consumed in-register
      bf16x8 ap1 = __builtin_bit_cast(bf16x8, u1);

#pragma unroll
      for (int cg = 0; cg < 4; ++cg) {
        o[cg][qh] = __builtin_amdgcn_mfma_f32_32x32x16_bf16(ap0, ha[cg], o[cg][qh], 0, 0, 0);
        o[cg][qh] = __builtin_amdgcn_mfma_f32_32x32x16_bf16(ap1, hb[cg], o[cg][qh], 0, 0, 0);
      }
    }

    af0 = naf0; af1 = naf1;
  }

  // ---- one-time kw-combine: bf16-packed partials through LDS ----
  lsh[kw][0][lan] = l2[0];
  lsh[kw][1][lan] = l2[1];
#pragma unroll
  for (int cgp = 0; cgp < 2; ++cgp)
#pragma unroll
    for (int qh = 0; qh < 2; ++qh)
#pragma unroll
      for (int r = 0; r < 16; ++r)
        pls[kw][cgp][qh][r][lan] = pk2(o[cgp * 2][qh][r], o[cgp * 2 + 1][qh][r]);
  __syncthreads();

  const int cgp = kw >> 1, qh = kw & 1;         // this wave's output slice
  float e0[16], e1[16];
#pragma unroll
  for (int r = 0; r < 16; ++r) { e0[r] = 0.f; e1[r] = 0.f; }
#pragma unroll
  for (int kk = 0; kk < 4; ++kk)
#pragma unroll
    for (int r = 0; r < 16; ++r) {
      u32 v = pls[kk][cgp][qh][r][lan];
      e0[r] += __builtin_bit_cast(float, v << 16);
      e1[r] += __builtin_bit_cast(float, v & 0xFFFF0000u);
    }
  const float l_tot = lsh[0][qh][lan] + lsh[1][qh][lan]
                    + lsh[2][qh][lan] + lsh[3][qh][lan];
  const float gi = gamma / l_tot;
#pragma unroll
  for (int r = 0; r < 16; ++r) {
    const int nl = (r & 3) + 8 * (r >> 2) + 4 * g2;
    const float gir = __shfl(gi, nl);
    const size_t row = (size_t)b * NSEQ + n0 + qh * 32 + nl;
    const size_t i0 = row * CDIM + cb * 128 + cgp * 64 + lan31;
    out[i0]      = fmaf(gir, e0[r], x[i0]);
    out[i0 + 32] = fmaf(gir, e1[r], x[i0 + 32]);
  }
}

extern "C" void kernel_launch(void* const* d_in, const int* in_sizes, int n_in,
                              void* d_out, int out_size, void* d_ws, size_t ws_size,
                              hipStream_t stream) {
  const float* x     = (const float*)d_in[0];
  const float* Wf    = (const float*)d_in[1];
  const float* bf    = (const float*)d_in[2];
  const float* Wg    = (const float*)d_in[3];
  const float* bg    = (const float*)d_in[4];
  const float* Wh    = (const float*)d_in[5];
  const float* bh    = (const float*)d_in[6];
  const float* gamma = (const float*)d_in[7];
  float* out = (float*)d_out;

  // layout: hP | fP | g | wfP | wgP | whP  (fP before g so f-prefetch overrun lands in g)
  u16* hP   = (u16*)d_ws;                                    // 8 MB
  u16* fPp  = hP  + (size_t)BATCH * CDIM * NSEQ;             // 1 MB
  u16* g_ws = fPp + (size_t)BATCH * NSEQ * CQK;              // 1 MB
  u16* wfP  = g_ws + (size_t)BATCH * NSEQ * CQK;             // 16 KB
  u16* wgP  = wfP + (size_t)CQK * CDIM;                      // 16 KB
  u16* whP  = wgP + (size_t)CQK * CDIM;                      // 128 KB

  hipLaunchKernelGGL(prep_kernel, dim3(160), dim3(64), 0, stream,
                     Wf, Wg, Wh, wfP, wgP, whP);
  hipLaunchKernelGGL(proj_kernel, dim3(256), dim3(512), 0, stream,
                     x, bf, bg, bh, wfP, wgP, whP, fPp, g_ws, hP);
  hipLaunchKernelGGL(attn_kernel, dim3(512), dim3(256), 0, stream,
                     x, gamma, fPp, g_ws, hP, out);
}

// Round 31
// 69.685 us; speedup vs baseline: 1.2956x; 1.0001x over previous
//
#include <hip/hip_runtime.h>
#include <hip/hip_bf16.h>

#define BATCH 4
#define NSEQ  4096
#define CDIM  256
#define CQK   32
#define L2E   1.44269504088896340736f

typedef short bf16x8 __attribute__((ext_vector_type(8)));   // 8 bf16 in 4 VGPRs
typedef float f32x16 __attribute__((ext_vector_type(16)));
typedef unsigned short u16;
typedef unsigned int   u32;
typedef unsigned int   u32x4 __attribute__((ext_vector_type(4)));

__device__ __forceinline__ u32 pk2(float lo, float hi) {    // v_cvt_pk_bf16_f32
  u16 a = __builtin_bit_cast(u16, __float2bfloat16(lo));
  u16 b = __builtin_bit_cast(u16, __float2bfloat16(hi));
  return (u32)a | ((u32)b << 16);
}
__device__ __forceinline__ bf16x8 ld8(const u16* p) {
  uint4 u = *(const uint4*)p;
  return __builtin_bit_cast(bf16x8, u);
}
// raw v_exp_f32 via builtin (hazard-safe; inline-asm version failed r9 at absmax 2.69)
__device__ __forceinline__ float exp2_raw(float x) {
#if __has_builtin(__builtin_amdgcn_exp2f)
  return __builtin_amdgcn_exp2f(x);
#else
  return exp2f(x);
#endif
}

// D-frag (regs=m, lane=n) -> fragment-of-transpose (lane holds n-row, j-slots=m), the
// attn-verified pk2+permlane pack. u0 = m in [0,16) (ks=0), u1 = m in [16,32) (ks=1).
__device__ __forceinline__ void dpack(const f32x16& acc, u32x4& u0, u32x4& u1) {
  u32 q0a = pk2(acc[0],acc[1]),   q0b = pk2(acc[2],acc[3]);
  u32 q1a = pk2(acc[4],acc[5]),   q1b = pk2(acc[6],acc[7]);
  u32 q2a = pk2(acc[8],acc[9]),   q2b = pk2(acc[10],acc[11]);
  u32 q3a = pk2(acc[12],acc[13]), q3b = pk2(acc[14],acc[15]);
  auto r02a = __builtin_amdgcn_permlane32_swap(q0a, q1a, false, false);
  auto r13a = __builtin_amdgcn_permlane32_swap(q0b, q1b, false, false);
  auto r02b = __builtin_amdgcn_permlane32_swap(q2a, q3a, false, false);
  auto r13b = __builtin_amdgcn_permlane32_swap(q2b, q3b, false, false);
  u0 = u32x4{(u32)r02a[0], (u32)r13a[0], (u32)r02a[1], (u32)r13a[1]};
  u1 = u32x4{(u32)r02b[0], (u32)r13b[0], (u32)r02b[1], (u32)r13b[1]};
}

// ---------------- weight prep -> FRAGMENT-PACKED weights (r27 measured-good) ------------
// wfP/wgP[ks(16)][lane(64)][8]; whP[cg(8)][ks(16)][lane(64)][8]. Same bytes serve as
// A- or B-operand fragments (layout duality). wfP pre-scaled by L2E.
__global__ __launch_bounds__(64) void prep_kernel(
    const float* __restrict__ Wf, const float* __restrict__ Wg, const float* __restrict__ Wh,
    u16* __restrict__ wfP, u16* __restrict__ wgP, u16* __restrict__ whP) {
  const int bid = blockIdx.x, l = threadIdx.x;
  const int c31 = l & 31, kh = l >> 5;
  if (bid < 32) {               // wf (0..15) / wg (16..31), tile = ks
    const bool isg = bid >= 16;
    const int ks = bid & 15;
    const float* W = isg ? Wg : Wf;
    const float scale = isg ? 1.0f : L2E;
    u16* dst = (isg ? wgP : wfP) + (size_t)(ks * 64 + l) * 8;
#pragma unroll
    for (int j = 0; j < 8; ++j) {
      const int k = ks * 16 + kh * 8 + j;
      dst[j] = (u16)(pk2(W[k * CQK + c31] * scale, 0.f) & 0xFFFF);
    }
  } else {                      // wh: tile = (cg, ks)
    const int t  = bid - 32;    // 0..127
    const int cg = t >> 4, ks = t & 15;
    u16* dst = whP + (size_t)((cg * 16 + ks) * 64 + l) * 8;
#pragma unroll
    for (int j = 0; j < 8; ++j) {
      const int k = ks * 16 + kh * 8 + j;
      dst[j] = (u16)(pk2(Wh[k * CDIM + cg * 32 + c31], 0.f) & 0xFFFF);
    }
  }
}

// ---------------- MFMA projection: 512-thr blocks, all outputs dpack'd + coalesced ------
// grid 256, 8 waves = (chunk 0/1) x (role 0..3); launch_bounds(512,4).
// r31: g now also computed with swapped operands (wgP as A, xf as B -> D[m=c][n=query])
// and dpack'd -> gP B-frag tiles, 2 coalesced stores (was 16 scatter u16 stores — the
// last scatter in the pipeline). attn's bgM loads become coalesced too.
// fP[b*128+kc][ks(2)][lane(64)][8]  : A-frag tiles for QK   (lane=key, j=c)
// gP[b*128+qc][ks(2)][lane(64)][8]  : B-frag tiles for QK   (lane=query, j=c)
// hP[(b*8+cg)*128+kc][ks(2)][lane(64)][8] : B-frag tiles for PV (lane=c, j=key)
__global__ __launch_bounds__(512, 4) void proj_kernel(
    const float* __restrict__ x,
    const float* __restrict__ bfv, const float* __restrict__ bgv, const float* __restrict__ bhv,
    const u16* __restrict__ wfP, const u16* __restrict__ wgP, const u16* __restrict__ whP,
    u16* __restrict__ fP, u16* __restrict__ gP, u16* __restrict__ hP) {
  __shared__ float xs[64][260];                 // +4 pad: 16B-aligned rows, bank-spread
  const int tid   = threadIdx.x;
  const int lan   = tid & 63;
  const int lan31 = lan & 31;
  const int g2    = lan >> 5;
  const int w8    = tid >> 6;                   // wave 0..7
  const int chunk = w8 >> 2;                    // key-chunk within block: 0/1
  const int w     = w8 & 3;                     // role 0..3
  const int row0  = blockIdx.x * 64 + chunk * 32;
  const int b     = row0 >> 12;
  const int kcg   = row0 >> 5;                  // global kc = b*128 + (row0&4095)>>5

  { // cooperative coalesced stage: 4096 float4s, 512 threads x 8 iters (8KB/instr)
    const float4* xg = (const float4*)(x + (size_t)(blockIdx.x * 64) * CDIM);
#pragma unroll
    for (int j = 0; j < 8; ++j) {
      const int idx = j * 512 + tid;            // float4 index in the 64x256 tile
      const int row = idx >> 6, c4 = idx & 63;
      *(float4*)&xs[row][c4 * 4] = xg[idx];
    }
  }
  __syncthreads();

  // per-wave x fragments from LDS (serve as A: row=xrow, or B: col=xrow — same bytes)
  const int xr = chunk * 32 + lan31;
  bf16x8 xf[16];
#pragma unroll
  for (int ks = 0; ks < 16; ++ks) {
    float4 a = *(const float4*)&xs[xr][ks * 16 + g2 * 8];
    float4 c = *(const float4*)&xs[xr][ks * 16 + g2 * 8 + 4];
    u32x4 u = { pk2(a.x, a.y), pk2(a.z, a.w), pk2(c.x, c.y), pk2(c.z, c.w) };
    xf[ks] = __builtin_bit_cast(bf16x8, u);
  }

  if (w < 2) { // f (w0) / g (w1): D[m=c][n=row] via (wP as A, xf as B); dpack -> tile
    const u16*  wP = w ? wgP : wfP;
    const float bscale = w ? 1.0f : L2E;
    const float* bv = w ? bgv : bfv;
    f32x16 acc;
#pragma unroll
    for (int r = 0; r < 16; ++r)
      acc[r] = bv[(r & 3) + 8 * (r >> 2) + 4 * g2] * bscale;  // bias per m=c (reg index)
#pragma unroll
    for (int ks = 0; ks < 16; ++ks)
      acc = __builtin_amdgcn_mfma_f32_32x32x16_bf16(ld8(wP + ks * 512 + lan * 8), xf[ks],
                                                    acc, 0, 0, 0);
    u32x4 u0, u1;
    dpack(acc, u0, u1);                         // lane=row (key/query), j=c
    u16* db = (w ? gP : fP) + (size_t)kcg * 1024 + lan * 8;
    *(uint4*)db         = __builtin_bit_cast(uint4, u0);    // c 0..15  (ks=0)
    *(uint4*)(db + 512) = __builtin_bit_cast(uint4, u1);    // c 16..31 (ks=1)
  }

  // h: role w handles channel groups {2w, 2w+1}; D[m=key][n=c] via (xf as A, whP as B);
  // dpack -> hP B-frag tile (lane=c, j=key) stored coalesced.
#pragma unroll
  for (int t = 0; t < 2; ++t) {
    const int cg = w * 2 + t;
    const int ct = cg * 32;
    f32x16 acc;
#pragma unroll
    for (int r = 0; r < 16; ++r) acc[r] = bhv[ct + lan31];  // bias per n=c (lane)
    const u16* wP = whP + (size_t)(cg * 16) * 512 + lan * 8;
#pragma unroll
    for (int ks = 0; ks < 16; ++ks)
      acc = __builtin_amdgcn_mfma_f32_32x32x16_bf16(xf[ks], ld8(wP + ks * 512), acc, 0, 0, 0);
    u32x4 u0, u1;
    dpack(acc, u0, u1);                         // lane=c, j=key
    u16* hb = hP + ((size_t)(b * 8 + cg) * 128 + ((row0 & (NSEQ - 1)) >> 5)) * 1024 + lan * 8;
    *(uint4*)hb         = __builtin_bit_cast(uint4, u0);    // keys 0..15  (ks=0)
    *(uint4*)(hb + 512) = __builtin_bit_cast(uint4, u1);    // keys 16..31 (ks=1)
  }
}

// ---------------- flash attention: barrier-free main loop (r22/r24 proven 54.6us) -------
// Grid 512 = 4b x 64 q-tiles(64q) x 2 cb -> 2 independent blocks/CU. Block = 4 waves =
// 4 key-splits; wave (kw): 64q x 128ch x 1024 keys. P consumed in-register; zero in-loop
// barriers/LDS; one-time kw-combine epilogue. bgM now loads coalesced from gP tiles.
// Measured dead ends from this config: setprio (r23 +10%), owner-rotation (r19 +60%),
// forced 4 waves/SIMD (r20 spill +690%), softmax pipelining (r25 +24%). Cross-block
// wave overlap at 2 blocks/CU IS the latency hiding; register budget (128 acc + ~116
// VGPR ~= 244/256) pins occupancy and unroll depth.
__global__ __launch_bounds__(256, 2) void attn_kernel(
    const float* __restrict__ x, const float* __restrict__ gamma_p,
    const u16* __restrict__ fP, const u16* __restrict__ gP,
    const u16* __restrict__ hP, float* __restrict__ out) {
  __shared__ u32   pls[4][2][2][16][64];        // [kw][cgp][qh][r][lane] 64KB combine
  __shared__ float lsh[4][2][64];               // [kw][qh][lane] 2KB

  const int tid   = threadIdx.x;
  const int lan   = tid & 63;
  const int lan31 = lan & 31;
  const int g2    = lan >> 5;
  const int kw    = tid >> 6;                   // wave id = key split 0..3
  const int bid   = blockIdx.x;
  const int xcd   = bid & 7;
  const int b     = xcd >> 1;
  const int inner = bid >> 3;                   // 0..63
  const int cb    = inner & 1;                  // channel block 0/1 (128 ch)
  const int n0    = ((((xcd & 1) << 5) | (inner >> 1))) * 64;

  const float gamma = gamma_p[0];

  // g fragments for both 32-query tiles (coalesced from gP tiles)
  bf16x8 bgM[2][2];
#pragma unroll
  for (int qh = 0; qh < 2; ++qh) {
    const u16* gp = gP + (size_t)(b * 128 + (n0 >> 5) + qh) * 1024 + lan * 8;
    bgM[qh][0] = ld8(gp);
    bgM[qh][1] = ld8(gp + 512);
  }

  f32x16 o[4][2], zfrag;                        // [cg][qh] = 128 acc regs
#pragma unroll
  for (int r = 0; r < 16; ++r) zfrag[r] = 0.f;
#pragma unroll
  for (int cg = 0; cg < 4; ++cg) { o[cg][0] = zfrag; o[cg][1] = zfrag; }
  float l2[2] = {0.f, 0.f};

  const u16*  fpk = fP + (size_t)(b * 128 + kw * 32) * 1024 + lan * 8;
  const u16*  hpk = hP + ((size_t)(b * 8 + cb * 4) * 128 + kw * 32) * 1024 + lan * 8;
  const size_t hcg = (size_t)128 * 1024;        // cg stride in elems

  bf16x8 af0 = ld8(fpk), af1 = ld8(fpk + 512);
  fpk += 1024;

  for (int it = 0; it < 32; ++it) {
    bf16x8 naf0 = ld8(fpk), naf1 = ld8(fpk + 512);          // f prefetch (overrun -> gP)
    fpk += 1024;
    bf16x8 ha[4], hb[4];                        // h loads hide under softmax
#pragma unroll
    for (int cg = 0; cg < 4; ++cg) {
      ha[cg] = ld8(hpk + cg * hcg);
      hb[cg] = ld8(hpk + cg * hcg + 512);
    }
    hpk += 1024;

#pragma unroll
    for (int qh = 0; qh < 2; ++qh) {
      f32x16 s = __builtin_amdgcn_mfma_f32_32x32x16_bf16(af0, bgM[qh][0], zfrag, 0, 0, 0);
      s        = __builtin_amdgcn_mfma_f32_32x32x16_bf16(af1, bgM[qh][1], s,     0, 0, 0);

      float pv[16];
#pragma unroll
      for (int r = 0; r < 16; ++r) pv[r] = exp2_raw(s[r]);
      float rs = ((pv[0]+pv[1])+(pv[2]+pv[3])) + ((pv[4]+pv[5])+(pv[6]+pv[7]))
               + ((pv[8]+pv[9])+(pv[10]+pv[11])) + ((pv[12]+pv[13])+(pv[14]+pv[15]));
      auto rr = __builtin_amdgcn_permlane32_swap(__builtin_bit_cast(u32, rs),
                                                 __builtin_bit_cast(u32, rs), false, false);
      l2[qh] += __builtin_bit_cast(float, (u32)rr[0]) + __builtin_bit_cast(float, (u32)rr[1]);

      f32x16 pvv;
#pragma unroll
      for (int r = 0; r < 16; ++r) pvv[r] = pv[r];
      u32x4 u0, u1;
      dpack(pvv, u0, u1);
      bf16x8 ap0 = __builtin_bit_cast(bf16x8, u0);          // consumed in-register
      bf16x8 ap1 = __builtin_bit_cast(bf16x8, u1);

#pragma unroll
      for (int cg = 0; cg < 4; ++cg) {
        o[cg][qh] = __builtin_amdgcn_mfma_f32_32x32x16_bf16(ap0, ha[cg], o[cg][qh], 0, 0, 0);
        o[cg][qh] = __builtin_amdgcn_mfma_f32_32x32x16_bf16(ap1, hb[cg], o[cg][qh], 0, 0, 0);
      }
    }

    af0 = naf0; af1 = naf1;
  }

  // ---- one-time kw-combine: bf16-packed partials through LDS ----
  lsh[kw][0][lan] = l2[0];
  lsh[kw][1][lan] = l2[1];
#pragma unroll
  for (int cgp = 0; cgp < 2; ++cgp)
#pragma unroll
    for (int qh = 0; qh < 2; ++qh)
#pragma unroll
      for (int r = 0; r < 16; ++r)
        pls[kw][cgp][qh][r][lan] = pk2(o[cgp * 2][qh][r], o[cgp * 2 + 1][qh][r]);
  __syncthreads();

  const int cgp = kw >> 1, qh = kw & 1;         // this wave's output slice
  float e0[16], e1[16];
#pragma unroll
  for (int r = 0; r < 16; ++r) { e0[r] = 0.f; e1[r] = 0.f; }
#pragma unroll
  for (int kk = 0; kk < 4; ++kk)
#pragma unroll
    for (int r = 0; r < 16; ++r) {
      u32 v = pls[kk][cgp][qh][r][lan];
      e0[r] += __builtin_bit_cast(float, v << 16);
      e1[r] += __builtin_bit_cast(float, v & 0xFFFF0000u);
    }
  const float l_tot = lsh[0][qh][lan] + lsh[1][qh][lan]
                    + lsh[2][qh][lan] + lsh[3][qh][lan];
  const float gi = gamma / l_tot;
#pragma unroll
  for (int r = 0; r < 16; ++r) {
    const int nl = (r & 3) + 8 * (r >> 2) + 4 * g2;
    const float gir = __shfl(gi, nl);
    const size_t row = (size_t)b * NSEQ + n0 + qh * 32 + nl;
    const size_t i0 = row * CDIM + cb * 128 + cgp * 64 + lan31;
    out[i0]      = fmaf(gir, e0[r], x[i0]);
    out[i0 + 32] = fmaf(gir, e1[r], x[i0 + 32]);
  }
}

extern "C" void kernel_launch(void* const* d_in, const int* in_sizes, int n_in,
                              void* d_out, int out_size, void* d_ws, size_t ws_size,
                              hipStream_t stream) {
  const float* x     = (const float*)d_in[0];
  const float* Wf    = (const float*)d_in[1];
  const float* bf    = (const float*)d_in[2];
  const float* Wg    = (const float*)d_in[3];
  const float* bg    = (const float*)d_in[4];
  const float* Wh    = (const float*)d_in[5];
  const float* bh    = (const float*)d_in[6];
  const float* gamma = (const float*)d_in[7];
  float* out = (float*)d_out;

  // layout: hP | fP | gP | wfP | wgP | whP  (fP before gP so f-prefetch overrun is safe)
  u16* hP   = (u16*)d_ws;                                    // 8 MB
  u16* fPp  = hP  + (size_t)BATCH * CDIM * NSEQ;             // 1 MB
  u16* gPp  = fPp + (size_t)BATCH * NSEQ * CQK;              // 1 MB
  u16* wfP  = gPp + (size_t)BATCH * NSEQ * CQK;              // 16 KB
  u16* wgP  = wfP + (size_t)CQK * CDIM;                      // 16 KB
  u16* whP  = wgP + (size_t)CQK * CDIM;                      // 128 KB

  hipLaunchKernelGGL(prep_kernel, dim3(160), dim3(64), 0, stream,
                     Wf, Wg, Wh, wfP, wgP, whP);
  hipLaunchKernelGGL(proj_kernel, dim3(256), dim3(512), 0, stream,
                     x, bf, bg, bh, wfP, wgP, whP, fPp, gPp, hP);
  hipLaunchKernelGGL(attn_kernel, dim3(512), dim3(256), 0, stream,
                     x, gamma, fPp, gPp, hP, out);
}